// Round 2
// baseline (1072.100 us; speedup 1.0000x reference)
//
#include <hip/hip_runtime.h>
#include <cstdint>
#include <cstddef>

#define N_NODES_C 100000
#define NF 64   // feature width for both aggregations

static inline size_t align256(size_t x) { return (x + 255) & ~size_t(255); }

// ---------- degree ----------
__global__ void deg_kernel(const int* __restrict__ dst, int E, int* __restrict__ deg) {
    int i = blockIdx.x * blockDim.x + threadIdx.x;
    int stride = gridDim.x * blockDim.x;
    for (; i < E; i += stride) atomicAdd(&deg[dst[i]], 1);
}

// ---------- scan phase A: per-block (256 elem) sums ----------
__global__ __launch_bounds__(256) void scan_blocks(const int* __restrict__ deg,
                                                   int* __restrict__ blocksum, int n) {
    int i = blockIdx.x * 256 + threadIdx.x;
    int v = (i < n) ? deg[i] : 0;
    int lane = threadIdx.x & 63, wid = threadIdx.x >> 6;
    int s = v;
    #pragma unroll
    for (int d = 1; d < 64; d <<= 1) s += __shfl_xor(s, d, 64);
    __shared__ int wsum[4];
    if (lane == 0) wsum[wid] = s;
    __syncthreads();
    if (threadIdx.x == 0) blocksum[blockIdx.x] = wsum[0] + wsum[1] + wsum[2] + wsum[3];
}

// ---------- scan phase B: exclusive scan of block sums (1 wave) ----------
__global__ void scan_mid(const int* __restrict__ blocksum, int* __restrict__ blockoff, int nblocks) {
    int lane = threadIdx.x;  // 64 threads
    int base = 0;
    for (int c = 0; c < nblocks; c += 64) {
        int idx = c + lane;
        int v = (idx < nblocks) ? blocksum[idx] : 0;
        int x = v;
        #pragma unroll
        for (int d = 1; d < 64; d <<= 1) {
            int y = __shfl_up(x, d, 64);
            if (lane >= d) x += y;
        }
        if (idx < nblocks) blockoff[idx] = base + x - v;
        base += __shfl(x, 63, 64);
    }
}

// ---------- scan phase C: full exclusive scan -> row_start, cursor, dinv ----------
__global__ __launch_bounds__(256) void scan_final(const int* __restrict__ deg,
                                                  const int* __restrict__ blockoff,
                                                  int* __restrict__ row_start,
                                                  int* __restrict__ cursor,
                                                  float* __restrict__ dinv, int n) {
    int i = blockIdx.x * 256 + threadIdx.x;
    int v = (i < n) ? deg[i] : 0;
    int lane = threadIdx.x & 63, wid = threadIdx.x >> 6;
    int x = v;
    #pragma unroll
    for (int d = 1; d < 64; d <<= 1) {
        int y = __shfl_up(x, d, 64);
        if (lane >= d) x += y;
    }
    __shared__ int wsum[4];
    if (lane == 63) wsum[wid] = x;
    __syncthreads();
    int woff = 0;
    for (int w = 0; w < wid; ++w) woff += wsum[w];
    int excl = blockoff[blockIdx.x] + woff + x - v;
    if (i < n) {
        row_start[i] = excl;
        cursor[i] = excl;
        dinv[i] = rsqrtf((float)(v + 1));   // +1 self-loop
        if (i == n - 1) row_start[n] = excl + v;
    }
}

// ---------- counting-sort scatter: edges sorted by dst ----------
__global__ void scatter_kernel(const int* __restrict__ src, const int* __restrict__ dst,
                               int E, int* __restrict__ cursor, int* __restrict__ sorted_src) {
    int i = blockIdx.x * blockDim.x + threadIdx.x;
    int stride = gridDim.x * blockDim.x;
    for (; i < E; i += stride) {
        int d = dst[i];
        int p = atomicAdd(&cursor[d], 1);
        sorted_src[p] = src[i];
    }
}

// ---------- pull aggregation: out[i] = dinv[i]*sum_{s in N(i)} dinv[s]*X[s] + dinv[i]^2*X[i] (+bias) ----------
__global__ __launch_bounds__(256) void agg_kernel(const float* __restrict__ X,
                                                  const float* __restrict__ dinv,
                                                  const int* __restrict__ row_start,
                                                  const int* __restrict__ sorted_src,
                                                  const float* __restrict__ bias,
                                                  float* __restrict__ out, int n) {
    int lane = threadIdx.x & 63;
    int wid = threadIdx.x >> 6;
    int wave = blockIdx.x * (blockDim.x >> 6) + wid;
    int nwaves = gridDim.x * (blockDim.x >> 6);
    for (int i = wave; i < n; i += nwaves) {
        int s0 = row_start[i], s1 = row_start[i + 1];
        float acc = 0.f, acc2 = 0.f;
        int j = s0;
        for (; j + 1 < s1; j += 2) {
            int sA = sorted_src[j], sB = sorted_src[j + 1];
            float dA = dinv[sA], dB = dinv[sB];
            float xA = X[(size_t)sA * NF + lane];
            float xB = X[(size_t)sB * NF + lane];
            acc  = fmaf(dA, xA, acc);
            acc2 = fmaf(dB, xB, acc2);
        }
        if (j < s1) {
            int sA = sorted_src[j];
            acc = fmaf(dinv[sA], X[(size_t)sA * NF + lane], acc);
        }
        acc += acc2;
        float di = dinv[i];
        float self = X[(size_t)i * NF + lane];
        float r = di * acc + di * di * self;
        if (bias) r += bias[lane];
        out[(size_t)i * NF + lane] = r;
    }
}

// ---------- fused per-row: t = relu(a @ W1 + b1) @ W2 ----------
// LDS: 32KB (W1) + 32KB (W2) = 64KB exactly. b1 read per-lane from global (L2-hit).
// Safe to alias T == A (each wave reads only its own row before writing it).
__global__ __launch_bounds__(256) void gemm_fused(const float* A,
                                                  const float* __restrict__ W1,
                                                  const float* __restrict__ b1,
                                                  const float* __restrict__ W2,
                                                  float* T, int n) {
    __shared__ float w1s[64 * 128];
    __shared__ float w2s[128 * 64];
    for (int idx = threadIdx.x; idx < 64 * 128; idx += blockDim.x) w1s[idx] = W1[idx];
    for (int idx = threadIdx.x; idx < 128 * 64; idx += blockDim.x) w2s[idx] = W2[idx];
    __syncthreads();

    int lane = threadIdx.x & 63;
    int wid = threadIdx.x >> 6;
    int wave = blockIdx.x * (blockDim.x >> 6) + wid;
    int nwaves = gridDim.x * (blockDim.x >> 6);
    float b1lo = b1[lane];
    float b1hi = b1[64 + lane];
    for (int i = wave; i < n; i += nwaves) {
        float x = A[(size_t)i * 64 + lane];
        float h0 = 0.f, h1 = 0.f;
        #pragma unroll
        for (int k = 0; k < 64; ++k) {
            float xk = __shfl(x, k, 64);
            h0 = fmaf(xk, w1s[k * 128 + lane], h0);
            h1 = fmaf(xk, w1s[k * 128 + 64 + lane], h1);
        }
        h0 = fmaxf(h0 + b1lo, 0.f);
        h1 = fmaxf(h1 + b1hi, 0.f);
        float t = 0.f;
        #pragma unroll
        for (int k = 0; k < 64; ++k) {
            float hk = __shfl(h0, k, 64);
            t = fmaf(hk, w2s[k * 64 + lane], t);
        }
        #pragma unroll
        for (int k = 0; k < 64; ++k) {
            float hk = __shfl(h1, k, 64);
            t = fmaf(hk, w2s[(64 + k) * 64 + lane], t);
        }
        T[(size_t)i * 64 + lane] = t;
    }
}

extern "C" void kernel_launch(void* const* d_in, const int* in_sizes, int n_in,
                              void* d_out, int out_size, void* d_ws, size_t ws_size,
                              hipStream_t stream) {
    const int* edge = (const int*)d_in[0];       // int32 (JAX x64 disabled)
    const float* emb = (const float*)d_in[1];
    const float* W1  = (const float*)d_in[2];
    const float* b1  = (const float*)d_in[3];
    const float* W2  = (const float*)d_in[4];
    const float* b2  = (const float*)d_in[5];
    int E = in_sizes[0] / 2;
    const int* src = edge;
    const int* dst = edge + E;
    int n = N_NODES_C;

    char* p = (char*)d_ws;
    int*   deg        = (int*)p;   p += align256((size_t)n * 4);
    int*   row_start  = (int*)p;   p += align256((size_t)(n + 1) * 4);
    int*   cursor     = (int*)p;   p += align256((size_t)n * 4);
    float* dinv       = (float*)p; p += align256((size_t)n * 4);
    int*   blocksum   = (int*)p;   p += align256(512 * 4);
    int*   blockoff   = (int*)p;   p += align256(512 * 4);
    int*   sorted_src = (int*)p;   p += align256((size_t)E * 4);
    float* agg1       = (float*)p; p += align256((size_t)n * NF * 4);

    hipMemsetAsync(deg, 0, (size_t)n * 4, stream);
    deg_kernel<<<2048, 256, 0, stream>>>(dst, E, deg);
    int nblk = (n + 255) / 256;
    scan_blocks<<<nblk, 256, 0, stream>>>(deg, blocksum, n);
    scan_mid<<<1, 64, 0, stream>>>(blocksum, blockoff, nblk);
    scan_final<<<nblk, 256, 0, stream>>>(deg, blockoff, row_start, cursor, dinv, n);
    scatter_kernel<<<2048, 256, 0, stream>>>(src, dst, E, cursor, sorted_src);

    // layer 1 aggregation in input space (64 wide), no bias
    agg_kernel<<<4096, 256, 0, stream>>>(emb, dinv, row_start, sorted_src, nullptr, agg1, n);
    // fused: t = relu(agg1 @ W1 + b1) @ W2   (in place)
    gemm_fused<<<2048, 256, 0, stream>>>(agg1, W1, b1, W2, agg1, n);
    // layer 2 aggregation + b2 -> out
    agg_kernel<<<4096, 256, 0, stream>>>(agg1, dinv, row_start, sorted_src, b2, (float*)d_out, n);
}

// Round 3
// 467.687 us; speedup vs baseline: 2.2923x; 2.2923x over previous
//
#include <hip/hip_runtime.h>
#include <cstdint>
#include <cstddef>

#define N_NODES_C 100000
#define NF 64   // feature width for both aggregations

static inline size_t align256(size_t x) { return (x + 255) & ~size_t(255); }

// ---------- degree ----------
__global__ void deg_kernel(const int* __restrict__ dst, int E, int* __restrict__ deg) {
    int i = blockIdx.x * blockDim.x + threadIdx.x;
    int stride = gridDim.x * blockDim.x;
    for (; i < E; i += stride) atomicAdd(&deg[dst[i]], 1);
}

// ---------- scan phase A: per-block (256 elem) sums ----------
__global__ __launch_bounds__(256) void scan_blocks(const int* __restrict__ deg,
                                                   int* __restrict__ blocksum, int n) {
    int i = blockIdx.x * 256 + threadIdx.x;
    int v = (i < n) ? deg[i] : 0;
    int lane = threadIdx.x & 63, wid = threadIdx.x >> 6;
    int s = v;
    #pragma unroll
    for (int d = 1; d < 64; d <<= 1) s += __shfl_xor(s, d, 64);
    __shared__ int wsum[4];
    if (lane == 0) wsum[wid] = s;
    __syncthreads();
    if (threadIdx.x == 0) blocksum[blockIdx.x] = wsum[0] + wsum[1] + wsum[2] + wsum[3];
}

// ---------- scan phase B: exclusive scan of block sums (1 wave) ----------
__global__ void scan_mid(const int* __restrict__ blocksum, int* __restrict__ blockoff, int nblocks) {
    int lane = threadIdx.x;  // 64 threads
    int base = 0;
    for (int c = 0; c < nblocks; c += 64) {
        int idx = c + lane;
        int v = (idx < nblocks) ? blocksum[idx] : 0;
        int x = v;
        #pragma unroll
        for (int d = 1; d < 64; d <<= 1) {
            int y = __shfl_up(x, d, 64);
            if (lane >= d) x += y;
        }
        if (idx < nblocks) blockoff[idx] = base + x - v;
        base += __shfl(x, 63, 64);
    }
}

// ---------- scan phase C: full exclusive scan -> row_start, cursor, dinv ----------
__global__ __launch_bounds__(256) void scan_final(const int* __restrict__ deg,
                                                  const int* __restrict__ blockoff,
                                                  int* __restrict__ row_start,
                                                  int* __restrict__ cursor,
                                                  float* __restrict__ dinv, int n) {
    int i = blockIdx.x * 256 + threadIdx.x;
    int v = (i < n) ? deg[i] : 0;
    int lane = threadIdx.x & 63, wid = threadIdx.x >> 6;
    int x = v;
    #pragma unroll
    for (int d = 1; d < 64; d <<= 1) {
        int y = __shfl_up(x, d, 64);
        if (lane >= d) x += y;
    }
    __shared__ int wsum[4];
    if (lane == 63) wsum[wid] = x;
    __syncthreads();
    int woff = 0;
    for (int w = 0; w < wid; ++w) woff += wsum[w];
    int excl = blockoff[blockIdx.x] + woff + x - v;
    if (i < n) {
        row_start[i] = excl;
        cursor[i] = excl;
        dinv[i] = rsqrtf((float)(v + 1));   // +1 self-loop
        if (i == n - 1) row_start[n] = excl + v;
    }
}

// ---------- counting-sort scatter: edges sorted by dst ----------
__global__ void scatter_kernel(const int* __restrict__ src, const int* __restrict__ dst,
                               int E, int* __restrict__ cursor, int* __restrict__ sorted_src) {
    int i = blockIdx.x * blockDim.x + threadIdx.x;
    int stride = gridDim.x * blockDim.x;
    for (; i < E; i += stride) {
        int d = dst[i];
        int p = atomicAdd(&cursor[d], 1);
        sorted_src[p] = src[i];
    }
}

// ---------- pull aggregation: out[i] = dinv[i]*sum_{s in N(i)} dinv[s]*X[s] + dinv[i]^2*X[i] (+bias) ----------
__global__ __launch_bounds__(256) void agg_kernel(const float* __restrict__ X,
                                                  const float* __restrict__ dinv,
                                                  const int* __restrict__ row_start,
                                                  const int* __restrict__ sorted_src,
                                                  const float* __restrict__ bias,
                                                  float* __restrict__ out, int n) {
    int lane = threadIdx.x & 63;
    int wid = threadIdx.x >> 6;
    int wave = blockIdx.x * (blockDim.x >> 6) + wid;
    int nwaves = gridDim.x * (blockDim.x >> 6);
    for (int i = wave; i < n; i += nwaves) {
        int s0 = row_start[i], s1 = row_start[i + 1];
        float acc = 0.f, acc2 = 0.f;
        int j = s0;
        for (; j + 1 < s1; j += 2) {
            int sA = sorted_src[j], sB = sorted_src[j + 1];
            float dA = dinv[sA], dB = dinv[sB];
            float xA = X[(size_t)sA * NF + lane];
            float xB = X[(size_t)sB * NF + lane];
            acc  = fmaf(dA, xA, acc);
            acc2 = fmaf(dB, xB, acc2);
        }
        if (j < s1) {
            int sA = sorted_src[j];
            acc = fmaf(dinv[sA], X[(size_t)sA * NF + lane], acc);
        }
        acc += acc2;
        float di = dinv[i];
        float self = X[(size_t)i * NF + lane];
        float r = di * acc + di * di * self;
        if (bias) r += bias[lane];
        out[(size_t)i * NF + lane] = r;
    }
}

// ---------- fused register-tiled GEMM: T = relu(A @ W1 + b1) @ W2 ----------
// Block = 256 threads, one 32-row tile (grid = 3125, exact).
// LDS union (50 KB): phase1 [A^T 64x36 | W1 64x128]  phase2 [W2 128x64 | h^T 128x36]
// Per k-step: 1 ds_read_b128 (A^T/h^T, conflict-free via stride 36) + 1 b128/b64 (W).
// Safe to alias T == A: tile rows fully staged to LDS before any write-back.
__global__ __launch_bounds__(256) void gemm_fused(const float* __restrict__ A,
                                                  const float* __restrict__ W1,
                                                  const float* __restrict__ b1,
                                                  const float* __restrict__ W2,
                                                  float* __restrict__ T) {
    __shared__ float lds[12800];            // 50 KB
    float* ldsA = lds;                      // [64][36]  (phase 1)
    float* w1s  = lds + 2304;               // [64][128] (phase 1)
    float* w2s  = lds;                      // [128][64] (phase 2)
    float* hT   = lds + 8192;               // [128][36] (phase 2)

    const int t = threadIdx.x;
    const int r0 = blockIdx.x * 32;
    const int rg = t & 7;                   // rows 4rg .. 4rg+3
    const int cg = t >> 3;                  // phase1 cols 4cg..+3 ; phase2 cols 2cg..+1

    // stage W1 (8192 floats, vectorized copy)
    {
        const float4* Wv = (const float4*)W1;
        float4* dv = (float4*)w1s;
        #pragma unroll
        for (int i = 0; i < 8; ++i) dv[t + 256 * i] = Wv[t + 256 * i];
    }
    // stage A tile transposed: [row][k] -> ldsA[k][row]
    #pragma unroll
    for (int i = 0; i < 2; ++i) {
        int q = t + 256 * i;                // 512 float4s
        int row = q >> 4;
        int k0 = (q & 15) << 2;
        float4 v = *(const float4*)&A[(size_t)(r0 + row) * 64 + k0];
        ldsA[(k0 + 0) * 36 + row] = v.x;
        ldsA[(k0 + 1) * 36 + row] = v.y;
        ldsA[(k0 + 2) * 36 + row] = v.z;
        ldsA[(k0 + 3) * 36 + row] = v.w;
    }
    float b1a[4];
    {
        float4 b1v = *(const float4*)&b1[4 * cg];
        b1a[0] = b1v.x; b1a[1] = b1v.y; b1a[2] = b1v.z; b1a[3] = b1v.w;
    }
    __syncthreads();

    // phase 1: h(32x128) = A(32x64) @ W1(64x128), 4x4 per thread
    float acc[4][4];
    #pragma unroll
    for (int i = 0; i < 4; ++i)
        #pragma unroll
        for (int j = 0; j < 4; ++j) acc[i][j] = 0.f;
    #pragma unroll 4
    for (int k = 0; k < 64; ++k) {
        float4 a = *(float4*)&ldsA[k * 36 + 4 * rg];
        float4 w = *(float4*)&w1s[k * 128 + 4 * cg];
        acc[0][0] = fmaf(a.x, w.x, acc[0][0]); acc[0][1] = fmaf(a.x, w.y, acc[0][1]);
        acc[0][2] = fmaf(a.x, w.z, acc[0][2]); acc[0][3] = fmaf(a.x, w.w, acc[0][3]);
        acc[1][0] = fmaf(a.y, w.x, acc[1][0]); acc[1][1] = fmaf(a.y, w.y, acc[1][1]);
        acc[1][2] = fmaf(a.y, w.z, acc[1][2]); acc[1][3] = fmaf(a.y, w.w, acc[1][3]);
        acc[2][0] = fmaf(a.z, w.x, acc[2][0]); acc[2][1] = fmaf(a.z, w.y, acc[2][1]);
        acc[2][2] = fmaf(a.z, w.z, acc[2][2]); acc[2][3] = fmaf(a.z, w.w, acc[2][3]);
        acc[3][0] = fmaf(a.w, w.x, acc[3][0]); acc[3][1] = fmaf(a.w, w.y, acc[3][1]);
        acc[3][2] = fmaf(a.w, w.z, acc[3][2]); acc[3][3] = fmaf(a.w, w.w, acc[3][3]);
    }
    __syncthreads();   // all phase-1 LDS reads done before overwrite

    // write h^T = relu(acc + b1), cols of this thread -> hT[c][r]
    #pragma unroll
    for (int jc = 0; jc < 4; ++jc) {
        float4 v;
        v.x = fmaxf(acc[0][jc] + b1a[jc], 0.f);
        v.y = fmaxf(acc[1][jc] + b1a[jc], 0.f);
        v.z = fmaxf(acc[2][jc] + b1a[jc], 0.f);
        v.w = fmaxf(acc[3][jc] + b1a[jc], 0.f);
        *(float4*)&hT[(4 * cg + jc) * 36 + 4 * rg] = v;
    }
    // stage W2 (8192 floats) into the freed region
    {
        const float4* Wv = (const float4*)W2;
        float4* dv = (float4*)w2s;
        #pragma unroll
        for (int i = 0; i < 8; ++i) dv[t + 256 * i] = Wv[t + 256 * i];
    }
    __syncthreads();

    // phase 2: t(32x64) = h(32x128) @ W2(128x64), 4x2 per thread
    float acc2[4][2];
    #pragma unroll
    for (int i = 0; i < 4; ++i) { acc2[i][0] = 0.f; acc2[i][1] = 0.f; }
    #pragma unroll 4
    for (int k = 0; k < 128; ++k) {
        float4 h = *(float4*)&hT[k * 36 + 4 * rg];
        float2 w = *(float2*)&w2s[k * 64 + 2 * cg];
        acc2[0][0] = fmaf(h.x, w.x, acc2[0][0]); acc2[0][1] = fmaf(h.x, w.y, acc2[0][1]);
        acc2[1][0] = fmaf(h.y, w.x, acc2[1][0]); acc2[1][1] = fmaf(h.y, w.y, acc2[1][1]);
        acc2[2][0] = fmaf(h.z, w.x, acc2[2][0]); acc2[2][1] = fmaf(h.z, w.y, acc2[2][1]);
        acc2[3][0] = fmaf(h.w, w.x, acc2[3][0]); acc2[3][1] = fmaf(h.w, w.y, acc2[3][1]);
    }
    #pragma unroll
    for (int i = 0; i < 4; ++i) {
        float2 o; o.x = acc2[i][0]; o.y = acc2[i][1];
        *(float2*)&T[(size_t)(r0 + 4 * rg + i) * 64 + 2 * cg] = o;
    }
}

extern "C" void kernel_launch(void* const* d_in, const int* in_sizes, int n_in,
                              void* d_out, int out_size, void* d_ws, size_t ws_size,
                              hipStream_t stream) {
    const int* edge = (const int*)d_in[0];       // int32 (JAX x64 disabled)
    const float* emb = (const float*)d_in[1];
    const float* W1  = (const float*)d_in[2];
    const float* b1  = (const float*)d_in[3];
    const float* W2  = (const float*)d_in[4];
    const float* b2  = (const float*)d_in[5];
    int E = in_sizes[0] / 2;
    const int* src = edge;
    const int* dst = edge + E;
    int n = N_NODES_C;

    char* p = (char*)d_ws;
    int*   deg        = (int*)p;   p += align256((size_t)n * 4);
    int*   row_start  = (int*)p;   p += align256((size_t)(n + 1) * 4);
    int*   cursor     = (int*)p;   p += align256((size_t)n * 4);
    float* dinv       = (float*)p; p += align256((size_t)n * 4);
    int*   blocksum   = (int*)p;   p += align256(512 * 4);
    int*   blockoff   = (int*)p;   p += align256(512 * 4);
    int*   sorted_src = (int*)p;   p += align256((size_t)E * 4);
    float* agg1       = (float*)p; p += align256((size_t)n * NF * 4);

    hipMemsetAsync(deg, 0, (size_t)n * 4, stream);
    deg_kernel<<<2048, 256, 0, stream>>>(dst, E, deg);
    int nblk = (n + 255) / 256;
    scan_blocks<<<nblk, 256, 0, stream>>>(deg, blocksum, n);
    scan_mid<<<1, 64, 0, stream>>>(blocksum, blockoff, nblk);
    scan_final<<<nblk, 256, 0, stream>>>(deg, blockoff, row_start, cursor, dinv, n);
    scatter_kernel<<<2048, 256, 0, stream>>>(src, dst, E, cursor, sorted_src);

    // layer 1 aggregation in input space (64 wide), no bias
    agg_kernel<<<4096, 256, 0, stream>>>(emb, dinv, row_start, sorted_src, nullptr, agg1, n);
    // fused: t = relu(agg1 @ W1 + b1) @ W2   (in place, 3125 x 32-row tiles)
    gemm_fused<<<3125, 256, 0, stream>>>(agg1, W1, b1, W2, agg1);
    // layer 2 aggregation + b2 -> out
    agg_kernel<<<4096, 256, 0, stream>>>(agg1, dinv, row_start, sorted_src, b2, (float*)d_out, n);
}

// Round 4
// 397.240 us; speedup vs baseline: 2.6989x; 1.1773x over previous
//
#include <hip/hip_runtime.h>
#include <cstdint>
#include <cstddef>

#define N_NODES_C 100000
#define NF 64   // feature width for both aggregations

static inline size_t align256(size_t x) { return (x + 255) & ~size_t(255); }

// bf16 helpers (no header dependency; RNE rounding)
__device__ inline float bf2f(unsigned short u) { return __uint_as_float(((unsigned)u) << 16); }
__device__ inline unsigned short f2bf(float x) {
    unsigned u = __float_as_uint(x);
    return (unsigned short)((u + 0x7fffu + ((u >> 16) & 1u)) >> 16);
}

// ---------- degree ----------
__global__ void deg_kernel(const int* __restrict__ dst, int E, int* __restrict__ deg) {
    int i = blockIdx.x * blockDim.x + threadIdx.x;
    int stride = gridDim.x * blockDim.x;
    for (; i < E; i += stride) atomicAdd(&deg[dst[i]], 1);
}

// ---------- scan phase A ----------
__global__ __launch_bounds__(256) void scan_blocks(const int* __restrict__ deg,
                                                   int* __restrict__ blocksum, int n) {
    int i = blockIdx.x * 256 + threadIdx.x;
    int v = (i < n) ? deg[i] : 0;
    int lane = threadIdx.x & 63, wid = threadIdx.x >> 6;
    int s = v;
    #pragma unroll
    for (int d = 1; d < 64; d <<= 1) s += __shfl_xor(s, d, 64);
    __shared__ int wsum[4];
    if (lane == 0) wsum[wid] = s;
    __syncthreads();
    if (threadIdx.x == 0) blocksum[blockIdx.x] = wsum[0] + wsum[1] + wsum[2] + wsum[3];
}

// ---------- scan phase B ----------
__global__ void scan_mid(const int* __restrict__ blocksum, int* __restrict__ blockoff, int nblocks) {
    int lane = threadIdx.x;  // 64 threads
    int base = 0;
    for (int c = 0; c < nblocks; c += 64) {
        int idx = c + lane;
        int v = (idx < nblocks) ? blocksum[idx] : 0;
        int x = v;
        #pragma unroll
        for (int d = 1; d < 64; d <<= 1) {
            int y = __shfl_up(x, d, 64);
            if (lane >= d) x += y;
        }
        if (idx < nblocks) blockoff[idx] = base + x - v;
        base += __shfl(x, 63, 64);
    }
}

// ---------- scan phase C ----------
__global__ __launch_bounds__(256) void scan_final(const int* __restrict__ deg,
                                                  const int* __restrict__ blockoff,
                                                  int* __restrict__ row_start,
                                                  int* __restrict__ cursor,
                                                  float* __restrict__ dinv, int n) {
    int i = blockIdx.x * 256 + threadIdx.x;
    int v = (i < n) ? deg[i] : 0;
    int lane = threadIdx.x & 63, wid = threadIdx.x >> 6;
    int x = v;
    #pragma unroll
    for (int d = 1; d < 64; d <<= 1) {
        int y = __shfl_up(x, d, 64);
        if (lane >= d) x += y;
    }
    __shared__ int wsum[4];
    if (lane == 63) wsum[wid] = x;
    __syncthreads();
    int woff = 0;
    for (int w = 0; w < wid; ++w) woff += wsum[w];
    int excl = blockoff[blockIdx.x] + woff + x - v;
    if (i < n) {
        row_start[i] = excl;
        cursor[i] = excl;
        dinv[i] = rsqrtf((float)(v + 1));   // +1 self-loop
        if (i == n - 1) row_start[n] = excl + v;
    }
}

// ---------- counting-sort scatter ----------
__global__ void scatter_kernel(const int* __restrict__ src, const int* __restrict__ dst,
                               int E, int* __restrict__ cursor, int* __restrict__ sorted_src) {
    int i = blockIdx.x * blockDim.x + threadIdx.x;
    int stride = gridDim.x * blockDim.x;
    for (; i < E; i += stride) {
        int d = dst[i];
        int p = atomicAdd(&cursor[d], 1);
        sorted_src[p] = src[i];
    }
}

// ---------- prescale: Xs1[s] = bf16(dinv[s] * emb[s]) ----------
__global__ __launch_bounds__(256) void scale_emb(const float* __restrict__ emb,
                                                 const float* __restrict__ dinv,
                                                 unsigned short* __restrict__ Xs, int nq) {
    int q = blockIdx.x * 256 + threadIdx.x;      // one float4 (4 features)
    if (q >= nq) return;
    int node = q >> 4;                            // 16 float4 per row
    float d = dinv[node];
    float4 v = ((const float4*)emb)[q];
    ushort4 u;
    u.x = f2bf(v.x * d); u.y = f2bf(v.y * d);
    u.z = f2bf(v.z * d); u.w = f2bf(v.w * d);
    *(ushort4*)&Xs[(size_t)q * 4] = u;
}

// ---------- pull aggregation over pre-scaled bf16 rows ----------
// out[i] = dinv[i] * ( sum_{s in N(i)} Xs[s] + Xs[i] ) + bias
// wave = 1 node; lane: e = lane>>4 (4 edge slots), c = lane&15 (features 4c..4c+3)
__global__ __launch_bounds__(256) void agg_bf16(const unsigned short* __restrict__ Xs,
                                                const float* __restrict__ dinv,
                                                const int* __restrict__ row_start,
                                                const int* __restrict__ sorted_src,
                                                const float* __restrict__ bias,
                                                float* __restrict__ out, int n) {
    int lane = threadIdx.x & 63;
    int wid = threadIdx.x >> 6;
    int wave = blockIdx.x * (blockDim.x >> 6) + wid;
    int nwaves = gridDim.x * (blockDim.x >> 6);
    int e = lane >> 4;
    int c = lane & 15;
    for (int i = wave; i < n; i += nwaves) {
        int s0 = row_start[i], s1 = row_start[i + 1];
        float a0 = 0.f, a1 = 0.f, a2 = 0.f, a3 = 0.f;
        for (int j = s0; j < s1; j += 4) {
            int sj = j + e;
            if (sj < s1) {
                int s = sorted_src[sj];
                ushort4 u = *(const ushort4*)&Xs[(size_t)s * NF + 4 * c];
                a0 += bf2f(u.x); a1 += bf2f(u.y); a2 += bf2f(u.z); a3 += bf2f(u.w);
            }
        }
        // reduce across the 4 edge slots (lane bits 4 and 5)
        a0 += __shfl_xor(a0, 16, 64); a1 += __shfl_xor(a1, 16, 64);
        a2 += __shfl_xor(a2, 16, 64); a3 += __shfl_xor(a3, 16, 64);
        a0 += __shfl_xor(a0, 32, 64); a1 += __shfl_xor(a1, 32, 64);
        a2 += __shfl_xor(a2, 32, 64); a3 += __shfl_xor(a3, 32, 64);
        if (e == 0) {
            float di = dinv[i];
            ushort4 u = *(const ushort4*)&Xs[(size_t)i * NF + 4 * c];   // self row
            a0 = di * (a0 + bf2f(u.x));
            a1 = di * (a1 + bf2f(u.y));
            a2 = di * (a2 + bf2f(u.z));
            a3 = di * (a3 + bf2f(u.w));
            if (bias) {
                float4 b = *(const float4*)&bias[4 * c];
                a0 += b.x; a1 += b.y; a2 += b.z; a3 += b.w;
            }
            float4 o; o.x = a0; o.y = a1; o.z = a2; o.w = a3;
            *(float4*)&out[(size_t)i * NF + 4 * c] = o;
        }
    }
}

// ---------- fused register-tiled GEMM: Tbf = bf16( dinv[row] * (relu(A@W1+b1) @ W2) ) ----------
// Block = 256 threads, one 32-row tile (grid = 3125, exact).
// LDS union (50 KB): phase1 [A^T 64x36 | W1 64x128]  phase2 [W2 128x64 | h^T 128x36]
__global__ __launch_bounds__(256) void gemm_fused(const float* __restrict__ A,
                                                  const float* __restrict__ W1,
                                                  const float* __restrict__ b1,
                                                  const float* __restrict__ W2,
                                                  const float* __restrict__ dinv,
                                                  unsigned short* __restrict__ Tbf) {
    __shared__ float lds[12800];            // 50 KB
    float* ldsA = lds;                      // [64][36]  (phase 1)
    float* w1s  = lds + 2304;               // [64][128] (phase 1)
    float* w2s  = lds;                      // [128][64] (phase 2)
    float* hT   = lds + 8192;               // [128][36] (phase 2)

    const int t = threadIdx.x;
    const int r0 = blockIdx.x * 32;
    const int rg = t & 7;                   // rows 4rg .. 4rg+3
    const int cg = t >> 3;                  // phase1 cols 4cg..+3 ; phase2 cols 2cg..+1

    {
        const float4* Wv = (const float4*)W1;
        float4* dv = (float4*)w1s;
        #pragma unroll
        for (int i = 0; i < 8; ++i) dv[t + 256 * i] = Wv[t + 256 * i];
    }
    #pragma unroll
    for (int i = 0; i < 2; ++i) {
        int q = t + 256 * i;                // 512 float4s
        int row = q >> 4;
        int k0 = (q & 15) << 2;
        float4 v = *(const float4*)&A[(size_t)(r0 + row) * 64 + k0];
        ldsA[(k0 + 0) * 36 + row] = v.x;
        ldsA[(k0 + 1) * 36 + row] = v.y;
        ldsA[(k0 + 2) * 36 + row] = v.z;
        ldsA[(k0 + 3) * 36 + row] = v.w;
    }
    float b1a[4];
    {
        float4 b1v = *(const float4*)&b1[4 * cg];
        b1a[0] = b1v.x; b1a[1] = b1v.y; b1a[2] = b1v.z; b1a[3] = b1v.w;
    }
    __syncthreads();

    // phase 1: h(32x128) = A(32x64) @ W1(64x128), 4x4 per thread
    float acc[4][4];
    #pragma unroll
    for (int i = 0; i < 4; ++i)
        #pragma unroll
        for (int j = 0; j < 4; ++j) acc[i][j] = 0.f;
    #pragma unroll 4
    for (int k = 0; k < 64; ++k) {
        float4 a = *(float4*)&ldsA[k * 36 + 4 * rg];
        float4 w = *(float4*)&w1s[k * 128 + 4 * cg];
        acc[0][0] = fmaf(a.x, w.x, acc[0][0]); acc[0][1] = fmaf(a.x, w.y, acc[0][1]);
        acc[0][2] = fmaf(a.x, w.z, acc[0][2]); acc[0][3] = fmaf(a.x, w.w, acc[0][3]);
        acc[1][0] = fmaf(a.y, w.x, acc[1][0]); acc[1][1] = fmaf(a.y, w.y, acc[1][1]);
        acc[1][2] = fmaf(a.y, w.z, acc[1][2]); acc[1][3] = fmaf(a.y, w.w, acc[1][3]);
        acc[2][0] = fmaf(a.z, w.x, acc[2][0]); acc[2][1] = fmaf(a.z, w.y, acc[2][1]);
        acc[2][2] = fmaf(a.z, w.z, acc[2][2]); acc[2][3] = fmaf(a.z, w.w, acc[2][3]);
        acc[3][0] = fmaf(a.w, w.x, acc[3][0]); acc[3][1] = fmaf(a.w, w.y, acc[3][1]);
        acc[3][2] = fmaf(a.w, w.z, acc[3][2]); acc[3][3] = fmaf(a.w, w.w, acc[3][3]);
    }
    __syncthreads();

    #pragma unroll
    for (int jc = 0; jc < 4; ++jc) {
        float4 v;
        v.x = fmaxf(acc[0][jc] + b1a[jc], 0.f);
        v.y = fmaxf(acc[1][jc] + b1a[jc], 0.f);
        v.z = fmaxf(acc[2][jc] + b1a[jc], 0.f);
        v.w = fmaxf(acc[3][jc] + b1a[jc], 0.f);
        *(float4*)&hT[(4 * cg + jc) * 36 + 4 * rg] = v;
    }
    {
        const float4* Wv = (const float4*)W2;
        float4* dv = (float4*)w2s;
        #pragma unroll
        for (int i = 0; i < 8; ++i) dv[t + 256 * i] = Wv[t + 256 * i];
    }
    __syncthreads();

    // phase 2: t(32x64) = h(32x128) @ W2(128x64), 4x2 per thread
    float acc2[4][2];
    #pragma unroll
    for (int i = 0; i < 4; ++i) { acc2[i][0] = 0.f; acc2[i][1] = 0.f; }
    #pragma unroll 4
    for (int k = 0; k < 128; ++k) {
        float4 h = *(float4*)&hT[k * 36 + 4 * rg];
        float2 w = *(float2*)&w2s[k * 64 + 2 * cg];
        acc2[0][0] = fmaf(h.x, w.x, acc2[0][0]); acc2[0][1] = fmaf(h.x, w.y, acc2[0][1]);
        acc2[1][0] = fmaf(h.y, w.x, acc2[1][0]); acc2[1][1] = fmaf(h.y, w.y, acc2[1][1]);
        acc2[2][0] = fmaf(h.z, w.x, acc2[2][0]); acc2[2][1] = fmaf(h.z, w.y, acc2[2][1]);
        acc2[3][0] = fmaf(h.w, w.x, acc2[3][0]); acc2[3][1] = fmaf(h.w, w.y, acc2[3][1]);
    }
    #pragma unroll
    for (int i = 0; i < 4; ++i) {
        int r = r0 + 4 * rg + i;
        float d = dinv[r];
        ushort2 pk;
        pk.x = f2bf(acc2[i][0] * d);
        pk.y = f2bf(acc2[i][1] * d);
        *(ushort2*)&Tbf[(size_t)r * 64 + 2 * cg] = pk;
    }
}

extern "C" void kernel_launch(void* const* d_in, const int* in_sizes, int n_in,
                              void* d_out, int out_size, void* d_ws, size_t ws_size,
                              hipStream_t stream) {
    const int* edge = (const int*)d_in[0];       // int32 (JAX x64 disabled)
    const float* emb = (const float*)d_in[1];
    const float* W1  = (const float*)d_in[2];
    const float* b1  = (const float*)d_in[3];
    const float* W2  = (const float*)d_in[4];
    const float* b2  = (const float*)d_in[5];
    int E = in_sizes[0] / 2;
    const int* src = edge;
    const int* dst = edge + E;
    int n = N_NODES_C;

    char* p = (char*)d_ws;
    int*   deg        = (int*)p;   p += align256((size_t)n * 4);
    int*   row_start  = (int*)p;   p += align256((size_t)(n + 1) * 4);
    int*   cursor     = (int*)p;   p += align256((size_t)n * 4);
    float* dinv       = (float*)p; p += align256((size_t)n * 4);
    int*   blocksum   = (int*)p;   p += align256(512 * 4);
    int*   blockoff   = (int*)p;   p += align256(512 * 4);
    int*   sorted_src = (int*)p;   p += align256((size_t)E * 4);
    float* agg1       = (float*)p; p += align256((size_t)n * NF * 4);
    unsigned short* Xs = (unsigned short*)p; p += align256((size_t)n * NF * 2);
    // Xs doubles as: layer-1 prescaled emb, then (after agg1 consumes it) layer-2 t_bf.

    hipMemsetAsync(deg, 0, (size_t)n * 4, stream);
    deg_kernel<<<2048, 256, 0, stream>>>(dst, E, deg);
    int nblk = (n + 255) / 256;
    scan_blocks<<<nblk, 256, 0, stream>>>(deg, blocksum, n);
    scan_mid<<<1, 64, 0, stream>>>(blocksum, blockoff, nblk);
    scan_final<<<nblk, 256, 0, stream>>>(deg, blockoff, row_start, cursor, dinv, n);
    scatter_kernel<<<2048, 256, 0, stream>>>(src, dst, E, cursor, sorted_src);

    // prescale emb by dinv into bf16
    int nq = n * 16;   // float4 count
    scale_emb<<<(nq + 255) / 256, 256, 0, stream>>>(emb, dinv, Xs, nq);
    // layer 1 aggregation (64 wide), no bias -> agg1 (f32)
    agg_bf16<<<4096, 256, 0, stream>>>(Xs, dinv, row_start, sorted_src, nullptr, agg1, n);
    // fused GEMM: Xs <- bf16( dinv * (relu(agg1@W1+b1)@W2) )   (Xs reuse is safe: agg1 done)
    gemm_fused<<<3125, 256, 0, stream>>>(agg1, W1, b1, W2, dinv, Xs);
    // layer 2 aggregation + b2 -> out (f32)
    agg_bf16<<<4096, 256, 0, stream>>>(Xs, dinv, row_start, sorted_src, b2, (float*)d_out, n);
}

// Round 5
// 289.013 us; speedup vs baseline: 3.7095x; 1.3745x over previous
//
#include <hip/hip_runtime.h>
#include <cstdint>
#include <cstddef>

#define N_NODES_C 100000
#define NF 64      // feature width for both aggregations
#define BW 512     // bucket width (nodes)
#define NB 196     // ceil(100000/512)
#define CHUNK 8192 // edges per bin_kernel block
#define SORT_CAP 9216

static inline size_t align256(size_t x) { return (x + 255) & ~size_t(255); }

// bf16 helpers (RNE rounding)
__device__ inline float bf2f(unsigned short u) { return __uint_as_float(((unsigned)u) << 16); }
__device__ inline unsigned short f2bf(float x) {
    unsigned u = __float_as_uint(x);
    return (unsigned short)((u + 0x7fffu + ((u >> 16) & 1u)) >> 16);
}

// ---------- degree ----------
__global__ void deg_kernel(const int* __restrict__ dst, int E, int* __restrict__ deg) {
    int i = blockIdx.x * blockDim.x + threadIdx.x;
    int stride = gridDim.x * blockDim.x;
    for (; i < E; i += stride) atomicAdd(&deg[dst[i]], 1);
}

// ---------- scan phase A ----------
__global__ __launch_bounds__(256) void scan_blocks(const int* __restrict__ deg,
                                                   int* __restrict__ blocksum, int n) {
    int i = blockIdx.x * 256 + threadIdx.x;
    int v = (i < n) ? deg[i] : 0;
    int lane = threadIdx.x & 63, wid = threadIdx.x >> 6;
    int s = v;
    #pragma unroll
    for (int d = 1; d < 64; d <<= 1) s += __shfl_xor(s, d, 64);
    __shared__ int wsum[4];
    if (lane == 0) wsum[wid] = s;
    __syncthreads();
    if (threadIdx.x == 0) blocksum[blockIdx.x] = wsum[0] + wsum[1] + wsum[2] + wsum[3];
}

// ---------- scan phase B ----------
__global__ void scan_mid(const int* __restrict__ blocksum, int* __restrict__ blockoff, int nblocks) {
    int lane = threadIdx.x;  // 64 threads
    int base = 0;
    for (int c = 0; c < nblocks; c += 64) {
        int idx = c + lane;
        int v = (idx < nblocks) ? blocksum[idx] : 0;
        int x = v;
        #pragma unroll
        for (int d = 1; d < 64; d <<= 1) {
            int y = __shfl_up(x, d, 64);
            if (lane >= d) x += y;
        }
        if (idx < nblocks) blockoff[idx] = base + x - v;
        base += __shfl(x, 63, 64);
    }
}

// ---------- scan phase C: row_start, dinv, bucket cursors ----------
__global__ __launch_bounds__(256) void scan_final(const int* __restrict__ deg,
                                                  const int* __restrict__ blockoff,
                                                  int* __restrict__ row_start,
                                                  int* __restrict__ bucket_cursor,
                                                  float* __restrict__ dinv, int n) {
    int i = blockIdx.x * 256 + threadIdx.x;
    int v = (i < n) ? deg[i] : 0;
    int lane = threadIdx.x & 63, wid = threadIdx.x >> 6;
    int x = v;
    #pragma unroll
    for (int d = 1; d < 64; d <<= 1) {
        int y = __shfl_up(x, d, 64);
        if (lane >= d) x += y;
    }
    __shared__ int wsum[4];
    if (lane == 63) wsum[wid] = x;
    __syncthreads();
    int woff = 0;
    for (int w = 0; w < wid; ++w) woff += wsum[w];
    int excl = blockoff[blockIdx.x] + woff + x - v;
    if (i < n) {
        row_start[i] = excl;
        if ((i & (BW - 1)) == 0) bucket_cursor[i >> 9] = excl;
        dinv[i] = rsqrtf((float)(v + 1));   // +1 self-loop
        if (i == n - 1) row_start[n] = excl + v;
    }
}

// ---------- pass B: coarse bucket binning, LDS-staged, coalesced output ----------
// packed entry = (src << 9) | (dst & 511); bucket = dst >> 9
__global__ __launch_bounds__(1024) void bin_kernel(const int* __restrict__ src,
                                                   const int* __restrict__ dst, int E,
                                                   int* __restrict__ bucket_cursor,
                                                   int* __restrict__ packed) {
    __shared__ int hist[NB];
    __shared__ int lbase[NB];
    __shared__ int lcur[NB];
    __shared__ int gbase[NB];
    __shared__ int stage[CHUNK];
    __shared__ unsigned char bid[CHUNK];
    int t = threadIdx.x;
    int e0 = blockIdx.x * CHUNK;
    int e1 = min(e0 + CHUNK, E);
    for (int i = t; i < NB; i += 1024) hist[i] = 0;
    __syncthreads();
    for (int e = e0 + t; e < e1; e += 1024) atomicAdd(&hist[dst[e] >> 9], 1);
    __syncthreads();
    // exclusive scan of hist (wave 0)
    if (t < 64) {
        int base = 0;
        for (int c = 0; c < NB; c += 64) {
            int idx = c + t;
            int v = (idx < NB) ? hist[idx] : 0;
            int x = v;
            #pragma unroll
            for (int d = 1; d < 64; d <<= 1) {
                int y = __shfl_up(x, d, 64);
                if (t >= d) x += y;
            }
            if (idx < NB) { lbase[idx] = base + x - v; lcur[idx] = base + x - v; }
            base += __shfl(x, 63, 64);
        }
    }
    __syncthreads();
    if (t < NB) gbase[t] = atomicAdd(&bucket_cursor[t], hist[t]);
    // block-local counting sort into stage
    for (int e = e0 + t; e < e1; e += 1024) {
        int d = dst[e];
        int b = d >> 9;
        int p = atomicAdd(&lcur[b], 1);
        stage[p] = (src[e] << 9) | (d & (BW - 1));
        bid[p] = (unsigned char)b;
    }
    __syncthreads();
    // coalesced copy-out (bucket-contiguous runs)
    int cnt = e1 - e0;
    for (int i = t; i < cnt; i += 1024) {
        int b = bid[i];
        packed[gbase[b] + (i - lbase[b])] = stage[i];
    }
}

// ---------- pass C: per-bucket exact counting sort -> sorted_src (coalesced) ----------
__global__ __launch_bounds__(512) void bucket_sort(const int* __restrict__ row_start,
                                                   const int* __restrict__ packed,
                                                   int* __restrict__ sorted_src, int n) {
    __shared__ int cur[BW];
    __shared__ int sorted[SORT_CAP];
    int b = blockIdx.x;
    int node0 = b * BW;
    int nn = min(BW, n - node0);
    int base = row_start[node0];
    int end = row_start[node0 + nn];
    int t = threadIdx.x;
    if (t < nn) cur[t] = row_start[node0 + t] - base;
    __syncthreads();
    int cnt = end - base;
    for (int i = t; i < cnt; i += 512) {
        int pk = packed[base + i];
        int p = atomicAdd(&cur[pk & (BW - 1)], 1);
        sorted[p] = pk >> 9;
    }
    __syncthreads();
    for (int i = t; i < cnt; i += 512) sorted_src[base + i] = sorted[i];
}

// ---------- prescale: Xs[s] = bf16(dinv[s] * emb[s]) ----------
__global__ __launch_bounds__(256) void scale_emb(const float* __restrict__ emb,
                                                 const float* __restrict__ dinv,
                                                 unsigned short* __restrict__ Xs, int nq) {
    int q = blockIdx.x * 256 + threadIdx.x;      // one float4 (4 features)
    if (q >= nq) return;
    int node = q >> 4;                            // 16 float4 per row
    float d = dinv[node];
    float4 v = ((const float4*)emb)[q];
    ushort4 u;
    u.x = f2bf(v.x * d); u.y = f2bf(v.y * d);
    u.z = f2bf(v.z * d); u.w = f2bf(v.w * d);
    *(ushort4*)&Xs[(size_t)q * 4] = u;
}

// ---------- pull aggregation over pre-scaled bf16 rows ----------
// out[i] = dinv[i] * ( sum_{s in N(i)} Xs[s] + Xs[i] ) + bias
__global__ __launch_bounds__(256) void agg_bf16(const unsigned short* __restrict__ Xs,
                                                const float* __restrict__ dinv,
                                                const int* __restrict__ row_start,
                                                const int* __restrict__ sorted_src,
                                                const float* __restrict__ bias,
                                                float* __restrict__ out, int n) {
    int lane = threadIdx.x & 63;
    int wid = threadIdx.x >> 6;
    int wave = blockIdx.x * (blockDim.x >> 6) + wid;
    int nwaves = gridDim.x * (blockDim.x >> 6);
    int e = lane >> 4;
    int c = lane & 15;
    for (int i = wave; i < n; i += nwaves) {
        int s0 = row_start[i], s1 = row_start[i + 1];
        float a0 = 0.f, a1 = 0.f, a2 = 0.f, a3 = 0.f;
        for (int j = s0; j < s1; j += 4) {
            int sj = j + e;
            if (sj < s1) {
                int s = sorted_src[sj];
                ushort4 u = *(const ushort4*)&Xs[(size_t)s * NF + 4 * c];
                a0 += bf2f(u.x); a1 += bf2f(u.y); a2 += bf2f(u.z); a3 += bf2f(u.w);
            }
        }
        a0 += __shfl_xor(a0, 16, 64); a1 += __shfl_xor(a1, 16, 64);
        a2 += __shfl_xor(a2, 16, 64); a3 += __shfl_xor(a3, 16, 64);
        a0 += __shfl_xor(a0, 32, 64); a1 += __shfl_xor(a1, 32, 64);
        a2 += __shfl_xor(a2, 32, 64); a3 += __shfl_xor(a3, 32, 64);
        if (e == 0) {
            float di = dinv[i];
            ushort4 u = *(const ushort4*)&Xs[(size_t)i * NF + 4 * c];   // self row
            a0 = di * (a0 + bf2f(u.x));
            a1 = di * (a1 + bf2f(u.y));
            a2 = di * (a2 + bf2f(u.z));
            a3 = di * (a3 + bf2f(u.w));
            if (bias) {
                float4 b = *(const float4*)&bias[4 * c];
                a0 += b.x; a1 += b.y; a2 += b.z; a3 += b.w;
            }
            float4 o; o.x = a0; o.y = a1; o.z = a2; o.w = a3;
            *(float4*)&out[(size_t)i * NF + 4 * c] = o;
        }
    }
}

// ---------- fused register-tiled GEMM: Tbf = bf16( dinv[row] * (relu(A@W1+b1) @ W2) ) ----------
__global__ __launch_bounds__(256) void gemm_fused(const float* __restrict__ A,
                                                  const float* __restrict__ W1,
                                                  const float* __restrict__ b1,
                                                  const float* __restrict__ W2,
                                                  const float* __restrict__ dinv,
                                                  unsigned short* __restrict__ Tbf) {
    __shared__ float lds[12800];            // 50 KB
    float* ldsA = lds;                      // [64][36]  (phase 1)
    float* w1s  = lds + 2304;               // [64][128] (phase 1)
    float* w2s  = lds;                      // [128][64] (phase 2)
    float* hT   = lds + 8192;               // [128][36] (phase 2)

    const int t = threadIdx.x;
    const int r0 = blockIdx.x * 32;
    const int rg = t & 7;                   // rows 4rg .. 4rg+3
    const int cg = t >> 3;                  // phase1 cols 4cg..+3 ; phase2 cols 2cg..+1

    {
        const float4* Wv = (const float4*)W1;
        float4* dv = (float4*)w1s;
        #pragma unroll
        for (int i = 0; i < 8; ++i) dv[t + 256 * i] = Wv[t + 256 * i];
    }
    #pragma unroll
    for (int i = 0; i < 2; ++i) {
        int q = t + 256 * i;                // 512 float4s
        int row = q >> 4;
        int k0 = (q & 15) << 2;
        float4 v = *(const float4*)&A[(size_t)(r0 + row) * 64 + k0];
        ldsA[(k0 + 0) * 36 + row] = v.x;
        ldsA[(k0 + 1) * 36 + row] = v.y;
        ldsA[(k0 + 2) * 36 + row] = v.z;
        ldsA[(k0 + 3) * 36 + row] = v.w;
    }
    float b1a[4];
    {
        float4 b1v = *(const float4*)&b1[4 * cg];
        b1a[0] = b1v.x; b1a[1] = b1v.y; b1a[2] = b1v.z; b1a[3] = b1v.w;
    }
    __syncthreads();

    float acc[4][4];
    #pragma unroll
    for (int i = 0; i < 4; ++i)
        #pragma unroll
        for (int j = 0; j < 4; ++j) acc[i][j] = 0.f;
    #pragma unroll 4
    for (int k = 0; k < 64; ++k) {
        float4 a = *(float4*)&ldsA[k * 36 + 4 * rg];
        float4 w = *(float4*)&w1s[k * 128 + 4 * cg];
        acc[0][0] = fmaf(a.x, w.x, acc[0][0]); acc[0][1] = fmaf(a.x, w.y, acc[0][1]);
        acc[0][2] = fmaf(a.x, w.z, acc[0][2]); acc[0][3] = fmaf(a.x, w.w, acc[0][3]);
        acc[1][0] = fmaf(a.y, w.x, acc[1][0]); acc[1][1] = fmaf(a.y, w.y, acc[1][1]);
        acc[1][2] = fmaf(a.y, w.z, acc[1][2]); acc[1][3] = fmaf(a.y, w.w, acc[1][3]);
        acc[2][0] = fmaf(a.z, w.x, acc[2][0]); acc[2][1] = fmaf(a.z, w.y, acc[2][1]);
        acc[2][2] = fmaf(a.z, w.z, acc[2][2]); acc[2][3] = fmaf(a.z, w.w, acc[2][3]);
        acc[3][0] = fmaf(a.w, w.x, acc[3][0]); acc[3][1] = fmaf(a.w, w.y, acc[3][1]);
        acc[3][2] = fmaf(a.w, w.z, acc[3][2]); acc[3][3] = fmaf(a.w, w.w, acc[3][3]);
    }
    __syncthreads();

    #pragma unroll
    for (int jc = 0; jc < 4; ++jc) {
        float4 v;
        v.x = fmaxf(acc[0][jc] + b1a[jc], 0.f);
        v.y = fmaxf(acc[1][jc] + b1a[jc], 0.f);
        v.z = fmaxf(acc[2][jc] + b1a[jc], 0.f);
        v.w = fmaxf(acc[3][jc] + b1a[jc], 0.f);
        *(float4*)&hT[(4 * cg + jc) * 36 + 4 * rg] = v;
    }
    {
        const float4* Wv = (const float4*)W2;
        float4* dv = (float4*)w2s;
        #pragma unroll
        for (int i = 0; i < 8; ++i) dv[t + 256 * i] = Wv[t + 256 * i];
    }
    __syncthreads();

    float acc2[4][2];
    #pragma unroll
    for (int i = 0; i < 4; ++i) { acc2[i][0] = 0.f; acc2[i][1] = 0.f; }
    #pragma unroll 4
    for (int k = 0; k < 128; ++k) {
        float4 h = *(float4*)&hT[k * 36 + 4 * rg];
        float2 w = *(float2*)&w2s[k * 64 + 2 * cg];
        acc2[0][0] = fmaf(h.x, w.x, acc2[0][0]); acc2[0][1] = fmaf(h.x, w.y, acc2[0][1]);
        acc2[1][0] = fmaf(h.y, w.x, acc2[1][0]); acc2[1][1] = fmaf(h.y, w.y, acc2[1][1]);
        acc2[2][0] = fmaf(h.z, w.x, acc2[2][0]); acc2[2][1] = fmaf(h.z, w.y, acc2[2][1]);
        acc2[3][0] = fmaf(h.w, w.x, acc2[3][0]); acc2[3][1] = fmaf(h.w, w.y, acc2[3][1]);
    }
    #pragma unroll
    for (int i = 0; i < 4; ++i) {
        int r = r0 + 4 * rg + i;
        float d = dinv[r];
        ushort2 pk;
        pk.x = f2bf(acc2[i][0] * d);
        pk.y = f2bf(acc2[i][1] * d);
        *(ushort2*)&Tbf[(size_t)r * 64 + 2 * cg] = pk;
    }
}

extern "C" void kernel_launch(void* const* d_in, const int* in_sizes, int n_in,
                              void* d_out, int out_size, void* d_ws, size_t ws_size,
                              hipStream_t stream) {
    const int* edge = (const int*)d_in[0];       // int32 (JAX x64 disabled)
    const float* emb = (const float*)d_in[1];
    const float* W1  = (const float*)d_in[2];
    const float* b1  = (const float*)d_in[3];
    const float* W2  = (const float*)d_in[4];
    const float* b2  = (const float*)d_in[5];
    int E = in_sizes[0] / 2;
    const int* src = edge;
    const int* dst = edge + E;
    int n = N_NODES_C;

    char* p = (char*)d_ws;
    int*   deg        = (int*)p;   p += align256((size_t)n * 4);
    int*   row_start  = (int*)p;   p += align256((size_t)(n + 1) * 4);
    float* dinv       = (float*)p; p += align256((size_t)n * 4);
    int*   blocksum   = (int*)p;   p += align256(512 * 4);
    int*   blockoff   = (int*)p;   p += align256(512 * 4);
    int*   bucket_cur = (int*)p;   p += align256(256 * 4);
    int*   sorted_src = (int*)p;   p += align256((size_t)E * 4);
    float* agg1       = (float*)p; p += align256((size_t)n * NF * 4);
    unsigned short* Xs = (unsigned short*)p; p += align256((size_t)n * NF * 2);
    // packed aliases agg1: packed lifetime [bin_kernel, bucket_sort] ends before agg1 is written
    int* packed = (int*)agg1;

    hipMemsetAsync(deg, 0, (size_t)n * 4, stream);
    deg_kernel<<<2048, 256, 0, stream>>>(dst, E, deg);
    int nblk = (n + 255) / 256;
    scan_blocks<<<nblk, 256, 0, stream>>>(deg, blocksum, n);
    scan_mid<<<1, 64, 0, stream>>>(blocksum, blockoff, nblk);
    scan_final<<<nblk, 256, 0, stream>>>(deg, blockoff, row_start, bucket_cur, dinv, n);

    // two-pass coalesced sort by dst
    int nbin = (E + CHUNK - 1) / CHUNK;
    bin_kernel<<<nbin, 1024, 0, stream>>>(src, dst, E, bucket_cur, packed);
    bucket_sort<<<NB, 512, 0, stream>>>(row_start, packed, sorted_src, n);

    // prescale emb by dinv into bf16
    int nq = n * 16;   // float4 count
    scale_emb<<<(nq + 255) / 256, 256, 0, stream>>>(emb, dinv, Xs, nq);
    // layer 1 aggregation (64 wide), no bias -> agg1 (f32)
    agg_bf16<<<4096, 256, 0, stream>>>(Xs, dinv, row_start, sorted_src, nullptr, agg1, n);
    // fused GEMM: Xs <- bf16( dinv * (relu(agg1@W1+b1)@W2) )
    gemm_fused<<<3125, 256, 0, stream>>>(agg1, W1, b1, W2, dinv, Xs);
    // layer 2 aggregation + b2 -> out (f32)
    agg_bf16<<<4096, 256, 0, stream>>>(Xs, dinv, row_start, sorted_src, b2, (float*)d_out, n);
}

// Round 6
// 228.263 us; speedup vs baseline: 4.6968x; 1.2661x over previous
//
#include <hip/hip_runtime.h>
#include <cstdint>
#include <cstddef>

#define N_NODES_C 100000
#define NF 64      // feature width for both aggregations
#define BW 512     // bucket width (nodes)
#define NB 196     // ceil(100000/512)
#define CHUNK 8192 // edges per chunk block
#define SORT_CAP 9216

static inline size_t align256(size_t x) { return (x + 255) & ~size_t(255); }

// bf16 helpers (RNE rounding)
__device__ inline float bf2f(unsigned short u) { return __uint_as_float(((unsigned)u) << 16); }
__device__ inline unsigned short f2bf(float x) {
    unsigned u = __float_as_uint(x);
    return (unsigned short)((u + 0x7fffu + ((u >> 16) & 1u)) >> 16);
}

// ---------- pass A: coarse bucket counts (196 global atomics per block) ----------
__global__ __launch_bounds__(1024) void bucket_count(const int* __restrict__ dst, int E,
                                                     int* __restrict__ counts) {
    __shared__ int hist[NB];
    int t = threadIdx.x;
    for (int i = t; i < NB; i += 1024) hist[i] = 0;
    __syncthreads();
    int e0 = blockIdx.x * CHUNK;
    int e1 = min(e0 + CHUNK, E);
    for (int e = e0 + t; e < e1; e += 1024) atomicAdd(&hist[dst[e] >> 9], 1);
    __syncthreads();
    for (int i = t; i < NB; i += 1024)
        if (hist[i]) atomicAdd(&counts[i], hist[i]);
}

// ---------- scan of 196 bucket counts (1 wave) ----------
__global__ void scan196(const int* __restrict__ counts, int* __restrict__ base196,
                        int* __restrict__ bucket_cursor, int* __restrict__ row_start, int n) {
    int lane = threadIdx.x;  // 64 threads
    int base = 0;
    for (int c = 0; c < NB; c += 64) {
        int idx = c + lane;
        int v = (idx < NB) ? counts[idx] : 0;
        int x = v;
        #pragma unroll
        for (int d = 1; d < 64; d <<= 1) {
            int y = __shfl_up(x, d, 64);
            if (lane >= d) x += y;
        }
        if (idx < NB) { base196[idx] = base + x - v; bucket_cursor[idx] = base + x - v; }
        base += __shfl(x, 63, 64);
    }
    if (lane == 0) { base196[NB] = base; row_start[n] = base; }
}

// ---------- pass B: coarse bucket binning, LDS-staged, coalesced output ----------
// packed entry = (src << 9) | (dst & 511); bucket = dst >> 9
__global__ __launch_bounds__(1024) void bin_kernel(const int* __restrict__ src,
                                                   const int* __restrict__ dst, int E,
                                                   int* __restrict__ bucket_cursor,
                                                   int* __restrict__ packed) {
    __shared__ int hist[NB];
    __shared__ int lbase[NB];
    __shared__ int lcur[NB];
    __shared__ int gbase[NB];
    __shared__ int stage[CHUNK];
    __shared__ unsigned char bid[CHUNK];
    int t = threadIdx.x;
    int e0 = blockIdx.x * CHUNK;
    int e1 = min(e0 + CHUNK, E);
    for (int i = t; i < NB; i += 1024) hist[i] = 0;
    __syncthreads();
    for (int e = e0 + t; e < e1; e += 1024) atomicAdd(&hist[dst[e] >> 9], 1);
    __syncthreads();
    if (t < 64) {
        int base = 0;
        for (int c = 0; c < NB; c += 64) {
            int idx = c + t;
            int v = (idx < NB) ? hist[idx] : 0;
            int x = v;
            #pragma unroll
            for (int d = 1; d < 64; d <<= 1) {
                int y = __shfl_up(x, d, 64);
                if (t >= d) x += y;
            }
            if (idx < NB) { lbase[idx] = base + x - v; lcur[idx] = base + x - v; }
            base += __shfl(x, 63, 64);
        }
    }
    __syncthreads();
    if (t < NB) gbase[t] = atomicAdd(&bucket_cursor[t], hist[t]);
    for (int e = e0 + t; e < e1; e += 1024) {
        int d = dst[e];
        int b = d >> 9;
        int p = atomicAdd(&lcur[b], 1);
        stage[p] = (src[e] << 9) | (d & (BW - 1));
        bid[p] = (unsigned char)b;
    }
    __syncthreads();
    int cnt = e1 - e0;
    for (int i = t; i < cnt; i += 1024) {
        int b = bid[i];
        packed[gbase[b] + (i - lbase[b])] = stage[i];
    }
}

// ---------- pass C: per-bucket degree + row_start + dinv + counting sort ----------
__global__ __launch_bounds__(512) void bucket_sort_deg(const int* __restrict__ base196,
                                                       const int* __restrict__ packed,
                                                       int* __restrict__ sorted_src,
                                                       int* __restrict__ row_start,
                                                       float* __restrict__ dinv, int n) {
    __shared__ int hist[BW];
    __shared__ int cur[BW];
    __shared__ int wsum[8];
    __shared__ int sorted[SORT_CAP];
    int b = blockIdx.x;
    int node0 = b * BW;
    int nn = min(BW, n - node0);
    int base = base196[b];
    int end = base196[b + 1];
    int cnt = end - base;
    int t = threadIdx.x;
    hist[t] = 0;
    __syncthreads();
    for (int i = t; i < cnt; i += 512) atomicAdd(&hist[packed[base + i] & (BW - 1)], 1);
    __syncthreads();
    // 512-wide exclusive scan of hist
    int v = hist[t];
    int lane = t & 63, w = t >> 6;
    int x = v;
    #pragma unroll
    for (int d = 1; d < 64; d <<= 1) {
        int y = __shfl_up(x, d, 64);
        if (lane >= d) x += y;
    }
    if (lane == 63) wsum[w] = x;
    __syncthreads();
    int woff = 0;
    for (int i = 0; i < w; ++i) woff += wsum[i];
    int excl = woff + x - v;
    cur[t] = excl;
    if (t < nn) {
        row_start[node0 + t] = base + excl;
        dinv[node0 + t] = rsqrtf((float)(v + 1));   // +1 self-loop
    }
    __syncthreads();
    for (int i = t; i < cnt; i += 512) {
        int pk = packed[base + i];
        int p = atomicAdd(&cur[pk & (BW - 1)], 1);
        sorted[p] = pk >> 9;
    }
    __syncthreads();
    for (int i = t; i < cnt; i += 512) sorted_src[base + i] = sorted[i];
}

// ---------- prescale: Xs[s] = bf16(dinv[s] * emb[s]) ----------
__global__ __launch_bounds__(256) void scale_emb(const float* __restrict__ emb,
                                                 const float* __restrict__ dinv,
                                                 unsigned short* __restrict__ Xs, int nq) {
    int q = blockIdx.x * 256 + threadIdx.x;      // one float4 (4 features)
    if (q >= nq) return;
    int node = q >> 4;                            // 16 float4 per row
    float d = dinv[node];
    float4 v = ((const float4*)emb)[q];
    ushort4 u;
    u.x = f2bf(v.x * d); u.y = f2bf(v.y * d);
    u.z = f2bf(v.z * d); u.w = f2bf(v.w * d);
    *(ushort4*)&Xs[(size_t)q * 4] = u;
}

// ---------- pull aggregation over pre-scaled bf16 rows ----------
// out[i] = dinv[i] * ( sum_{s in N(i)} Xs[s] + Xs[i] ) + bias
__global__ __launch_bounds__(256) void agg_bf16(const unsigned short* __restrict__ Xs,
                                                const float* __restrict__ dinv,
                                                const int* __restrict__ row_start,
                                                const int* __restrict__ sorted_src,
                                                const float* __restrict__ bias,
                                                float* __restrict__ out, int n) {
    int lane = threadIdx.x & 63;
    int wid = threadIdx.x >> 6;
    int wave = blockIdx.x * (blockDim.x >> 6) + wid;
    int nwaves = gridDim.x * (blockDim.x >> 6);
    int e = lane >> 4;
    int c = lane & 15;
    for (int i = wave; i < n; i += nwaves) {
        int s0 = row_start[i], s1 = row_start[i + 1];
        float a0 = 0.f, a1 = 0.f, a2 = 0.f, a3 = 0.f;
        for (int j = s0; j < s1; j += 4) {
            int sj = j + e;
            if (sj < s1) {
                int s = sorted_src[sj];
                ushort4 u = *(const ushort4*)&Xs[(size_t)s * NF + 4 * c];
                a0 += bf2f(u.x); a1 += bf2f(u.y); a2 += bf2f(u.z); a3 += bf2f(u.w);
            }
        }
        a0 += __shfl_xor(a0, 16, 64); a1 += __shfl_xor(a1, 16, 64);
        a2 += __shfl_xor(a2, 16, 64); a3 += __shfl_xor(a3, 16, 64);
        a0 += __shfl_xor(a0, 32, 64); a1 += __shfl_xor(a1, 32, 64);
        a2 += __shfl_xor(a2, 32, 64); a3 += __shfl_xor(a3, 32, 64);
        if (e == 0) {
            float di = dinv[i];
            ushort4 u = *(const ushort4*)&Xs[(size_t)i * NF + 4 * c];   // self row
            a0 = di * (a0 + bf2f(u.x));
            a1 = di * (a1 + bf2f(u.y));
            a2 = di * (a2 + bf2f(u.z));
            a3 = di * (a3 + bf2f(u.w));
            if (bias) {
                float4 bb = *(const float4*)&bias[4 * c];
                a0 += bb.x; a1 += bb.y; a2 += bb.z; a3 += bb.w;
            }
            float4 o; o.x = a0; o.y = a1; o.z = a2; o.w = a3;
            *(float4*)&out[(size_t)i * NF + 4 * c] = o;
        }
    }
}

// ---------- fused register-tiled GEMM: Tbf = bf16( dinv[row] * (relu(A@W1+b1) @ W2) ) ----------
__global__ __launch_bounds__(256) void gemm_fused(const float* __restrict__ A,
                                                  const float* __restrict__ W1,
                                                  const float* __restrict__ b1,
                                                  const float* __restrict__ W2,
                                                  const float* __restrict__ dinv,
                                                  unsigned short* __restrict__ Tbf) {
    __shared__ float lds[12800];            // 50 KB
    float* ldsA = lds;                      // [64][36]  (phase 1)
    float* w1s  = lds + 2304;               // [64][128] (phase 1)
    float* w2s  = lds;                      // [128][64] (phase 2)
    float* hT   = lds + 8192;               // [128][36] (phase 2)

    const int t = threadIdx.x;
    const int r0 = blockIdx.x * 32;
    const int rg = t & 7;                   // rows 4rg .. 4rg+3
    const int cg = t >> 3;                  // phase1 cols 4cg..+3 ; phase2 cols 2cg..+1

    {
        const float4* Wv = (const float4*)W1;
        float4* dv = (float4*)w1s;
        #pragma unroll
        for (int i = 0; i < 8; ++i) dv[t + 256 * i] = Wv[t + 256 * i];
    }
    #pragma unroll
    for (int i = 0; i < 2; ++i) {
        int q = t + 256 * i;                // 512 float4s
        int row = q >> 4;
        int k0 = (q & 15) << 2;
        float4 v = *(const float4*)&A[(size_t)(r0 + row) * 64 + k0];
        ldsA[(k0 + 0) * 36 + row] = v.x;
        ldsA[(k0 + 1) * 36 + row] = v.y;
        ldsA[(k0 + 2) * 36 + row] = v.z;
        ldsA[(k0 + 3) * 36 + row] = v.w;
    }
    float b1a[4];
    {
        float4 b1v = *(const float4*)&b1[4 * cg];
        b1a[0] = b1v.x; b1a[1] = b1v.y; b1a[2] = b1v.z; b1a[3] = b1v.w;
    }
    __syncthreads();

    float acc[4][4];
    #pragma unroll
    for (int i = 0; i < 4; ++i)
        #pragma unroll
        for (int j = 0; j < 4; ++j) acc[i][j] = 0.f;
    #pragma unroll 4
    for (int k = 0; k < 64; ++k) {
        float4 a = *(float4*)&ldsA[k * 36 + 4 * rg];
        float4 w = *(float4*)&w1s[k * 128 + 4 * cg];
        acc[0][0] = fmaf(a.x, w.x, acc[0][0]); acc[0][1] = fmaf(a.x, w.y, acc[0][1]);
        acc[0][2] = fmaf(a.x, w.z, acc[0][2]); acc[0][3] = fmaf(a.x, w.w, acc[0][3]);
        acc[1][0] = fmaf(a.y, w.x, acc[1][0]); acc[1][1] = fmaf(a.y, w.y, acc[1][1]);
        acc[1][2] = fmaf(a.y, w.z, acc[1][2]); acc[1][3] = fmaf(a.y, w.w, acc[1][3]);
        acc[2][0] = fmaf(a.z, w.x, acc[2][0]); acc[2][1] = fmaf(a.z, w.y, acc[2][1]);
        acc[2][2] = fmaf(a.z, w.z, acc[2][2]); acc[2][3] = fmaf(a.z, w.w, acc[2][3]);
        acc[3][0] = fmaf(a.w, w.x, acc[3][0]); acc[3][1] = fmaf(a.w, w.y, acc[3][1]);
        acc[3][2] = fmaf(a.w, w.z, acc[3][2]); acc[3][3] = fmaf(a.w, w.w, acc[3][3]);
    }
    __syncthreads();

    #pragma unroll
    for (int jc = 0; jc < 4; ++jc) {
        float4 v;
        v.x = fmaxf(acc[0][jc] + b1a[jc], 0.f);
        v.y = fmaxf(acc[1][jc] + b1a[jc], 0.f);
        v.z = fmaxf(acc[2][jc] + b1a[jc], 0.f);
        v.w = fmaxf(acc[3][jc] + b1a[jc], 0.f);
        *(float4*)&hT[(4 * cg + jc) * 36 + 4 * rg] = v;
    }
    {
        const float4* Wv = (const float4*)W2;
        float4* dv = (float4*)w2s;
        #pragma unroll
        for (int i = 0; i < 8; ++i) dv[t + 256 * i] = Wv[t + 256 * i];
    }
    __syncthreads();

    float acc2[4][2];
    #pragma unroll
    for (int i = 0; i < 4; ++i) { acc2[i][0] = 0.f; acc2[i][1] = 0.f; }
    #pragma unroll 4
    for (int k = 0; k < 128; ++k) {
        float4 h = *(float4*)&hT[k * 36 + 4 * rg];
        float2 w = *(float2*)&w2s[k * 64 + 2 * cg];
        acc2[0][0] = fmaf(h.x, w.x, acc2[0][0]); acc2[0][1] = fmaf(h.x, w.y, acc2[0][1]);
        acc2[1][0] = fmaf(h.y, w.x, acc2[1][0]); acc2[1][1] = fmaf(h.y, w.y, acc2[1][1]);
        acc2[2][0] = fmaf(h.z, w.x, acc2[2][0]); acc2[2][1] = fmaf(h.z, w.y, acc2[2][1]);
        acc2[3][0] = fmaf(h.w, w.x, acc2[3][0]); acc2[3][1] = fmaf(h.w, w.y, acc2[3][1]);
    }
    #pragma unroll
    for (int i = 0; i < 4; ++i) {
        int r = r0 + 4 * rg + i;
        float d = dinv[r];
        ushort2 pk;
        pk.x = f2bf(acc2[i][0] * d);
        pk.y = f2bf(acc2[i][1] * d);
        *(ushort2*)&Tbf[(size_t)r * 64 + 2 * cg] = pk;
    }
}

extern "C" void kernel_launch(void* const* d_in, const int* in_sizes, int n_in,
                              void* d_out, int out_size, void* d_ws, size_t ws_size,
                              hipStream_t stream) {
    const int* edge = (const int*)d_in[0];       // int32 (JAX x64 disabled)
    const float* emb = (const float*)d_in[1];
    const float* W1  = (const float*)d_in[2];
    const float* b1  = (const float*)d_in[3];
    const float* W2  = (const float*)d_in[4];
    const float* b2  = (const float*)d_in[5];
    int E = in_sizes[0] / 2;
    const int* src = edge;
    const int* dst = edge + E;
    int n = N_NODES_C;

    char* p = (char*)d_ws;
    int*   row_start  = (int*)p;   p += align256((size_t)(n + 1) * 4);
    float* dinv       = (float*)p; p += align256((size_t)n * 4);
    int*   bcounts    = (int*)p;   p += align256(256 * 4);
    int*   base196    = (int*)p;   p += align256(256 * 4);
    int*   bucket_cur = (int*)p;   p += align256(256 * 4);
    int*   sorted_src = (int*)p;   p += align256((size_t)E * 4);
    float* agg1       = (float*)p; p += align256((size_t)n * NF * 4);
    unsigned short* Xs = (unsigned short*)p; p += align256((size_t)n * NF * 2);
    // packed aliases agg1: its lifetime [bin_kernel, bucket_sort_deg] ends before agg1 is written
    int* packed = (int*)agg1;

    hipMemsetAsync(bcounts, 0, NB * 4, stream);
    int nbin = (E + CHUNK - 1) / CHUNK;
    bucket_count<<<nbin, 1024, 0, stream>>>(dst, E, bcounts);
    scan196<<<1, 64, 0, stream>>>(bcounts, base196, bucket_cur, row_start, n);
    bin_kernel<<<nbin, 1024, 0, stream>>>(src, dst, E, bucket_cur, packed);
    bucket_sort_deg<<<NB, 512, 0, stream>>>(base196, packed, sorted_src, row_start, dinv, n);

    // prescale emb by dinv into bf16
    int nq = n * 16;   // float4 count
    scale_emb<<<(nq + 255) / 256, 256, 0, stream>>>(emb, dinv, Xs, nq);
    // layer 1 aggregation (64 wide), no bias -> agg1 (f32)
    agg_bf16<<<4096, 256, 0, stream>>>(Xs, dinv, row_start, sorted_src, nullptr, agg1, n);
    // fused GEMM: Xs <- bf16( dinv * (relu(agg1@W1+b1)@W2) )
    gemm_fused<<<3125, 256, 0, stream>>>(agg1, W1, b1, W2, dinv, Xs);
    // layer 2 aggregation + b2 -> out (f32)
    agg_bf16<<<4096, 256, 0, stream>>>(Xs, dinv, row_start, sorted_src, b2, (float*)d_out, n);
}

// Round 7
// 193.485 us; speedup vs baseline: 5.5410x; 1.1797x over previous
//
#include <hip/hip_runtime.h>
#include <cstdint>
#include <cstddef>

#define N_NODES_C 100000
#define NF 64      // feature width for both aggregations
#define BW 512     // bucket width (nodes)
#define NB 196     // ceil(100000/512)
#define CHUNK 8192 // edges per chunk block
#define SORT_CAP 9216

static inline size_t align256(size_t x) { return (x + 255) & ~size_t(255); }

// bf16 helpers (RNE rounding)
__device__ inline float bf2f(unsigned short u) { return __uint_as_float(((unsigned)u) << 16); }
__device__ inline unsigned short f2bf(float x) {
    unsigned u = __float_as_uint(x);
    return (unsigned short)((u + 0x7fffu + ((u >> 16) & 1u)) >> 16);
}

// ---------- pass A: coarse bucket counts (196 global atomics per block) ----------
__global__ __launch_bounds__(1024) void bucket_count(const int* __restrict__ dst, int E,
                                                     int* __restrict__ counts) {
    __shared__ int hist[NB];
    int t = threadIdx.x;
    for (int i = t; i < NB; i += 1024) hist[i] = 0;
    __syncthreads();
    int e0 = blockIdx.x * CHUNK;
    int e1 = min(e0 + CHUNK, E);
    for (int e = e0 + t; e < e1; e += 1024) atomicAdd(&hist[dst[e] >> 9], 1);
    __syncthreads();
    for (int i = t; i < NB; i += 1024)
        if (hist[i]) atomicAdd(&counts[i], hist[i]);
}

// ---------- scan of 196 bucket counts (1 wave) ----------
__global__ void scan196(const int* __restrict__ counts, int* __restrict__ base196,
                        int* __restrict__ bucket_cursor, int* __restrict__ row_start, int n) {
    int lane = threadIdx.x;  // 64 threads
    int base = 0;
    for (int c = 0; c < NB; c += 64) {
        int idx = c + lane;
        int v = (idx < NB) ? counts[idx] : 0;
        int x = v;
        #pragma unroll
        for (int d = 1; d < 64; d <<= 1) {
            int y = __shfl_up(x, d, 64);
            if (lane >= d) x += y;
        }
        if (idx < NB) { base196[idx] = base + x - v; bucket_cursor[idx] = base + x - v; }
        base += __shfl(x, 63, 64);
    }
    if (lane == 0) { base196[NB] = base; row_start[n] = base; }
}

// ---------- pass B: coarse bucket binning, LDS-staged, coalesced output ----------
// packed entry = (src << 9) | (dst & 511); bucket = dst >> 9
__global__ __launch_bounds__(1024) void bin_kernel(const int* __restrict__ src,
                                                   const int* __restrict__ dst, int E,
                                                   int* __restrict__ bucket_cursor,
                                                   int* __restrict__ packed) {
    __shared__ int hist[NB];
    __shared__ int lbase[NB];
    __shared__ int lcur[NB];
    __shared__ int gbase[NB];
    __shared__ int stage[CHUNK];
    __shared__ unsigned char bid[CHUNK];
    int t = threadIdx.x;
    int e0 = blockIdx.x * CHUNK;
    int e1 = min(e0 + CHUNK, E);
    for (int i = t; i < NB; i += 1024) hist[i] = 0;
    __syncthreads();
    for (int e = e0 + t; e < e1; e += 1024) atomicAdd(&hist[dst[e] >> 9], 1);
    __syncthreads();
    if (t < 64) {
        int base = 0;
        for (int c = 0; c < NB; c += 64) {
            int idx = c + t;
            int v = (idx < NB) ? hist[idx] : 0;
            int x = v;
            #pragma unroll
            for (int d = 1; d < 64; d <<= 1) {
                int y = __shfl_up(x, d, 64);
                if (t >= d) x += y;
            }
            if (idx < NB) { lbase[idx] = base + x - v; lcur[idx] = base + x - v; }
            base += __shfl(x, 63, 64);
        }
    }
    __syncthreads();
    if (t < NB) gbase[t] = atomicAdd(&bucket_cursor[t], hist[t]);
    for (int e = e0 + t; e < e1; e += 1024) {
        int d = dst[e];
        int b = d >> 9;
        int p = atomicAdd(&lcur[b], 1);
        stage[p] = (src[e] << 9) | (d & (BW - 1));
        bid[p] = (unsigned char)b;
    }
    __syncthreads();
    int cnt = e1 - e0;
    for (int i = t; i < cnt; i += 1024) {
        int b = bid[i];
        packed[gbase[b] + (i - lbase[b])] = stage[i];
    }
}

// ---------- pass C: per-bucket degree + row_start + dinv + counting sort ----------
__global__ __launch_bounds__(512) void bucket_sort_deg(const int* __restrict__ base196,
                                                       const int* __restrict__ packed,
                                                       int* __restrict__ sorted_src,
                                                       int* __restrict__ row_start,
                                                       float* __restrict__ dinv, int n) {
    __shared__ int hist[BW];
    __shared__ int cur[BW];
    __shared__ int wsum[8];
    __shared__ int sorted[SORT_CAP];
    int b = blockIdx.x;
    int node0 = b * BW;
    int nn = min(BW, n - node0);
    int base = base196[b];
    int end = base196[b + 1];
    int cnt = end - base;
    int t = threadIdx.x;
    hist[t] = 0;
    __syncthreads();
    for (int i = t; i < cnt; i += 512) atomicAdd(&hist[packed[base + i] & (BW - 1)], 1);
    __syncthreads();
    // 512-wide exclusive scan of hist
    int v = hist[t];
    int lane = t & 63, w = t >> 6;
    int x = v;
    #pragma unroll
    for (int d = 1; d < 64; d <<= 1) {
        int y = __shfl_up(x, d, 64);
        if (lane >= d) x += y;
    }
    if (lane == 63) wsum[w] = x;
    __syncthreads();
    int woff = 0;
    for (int i = 0; i < w; ++i) woff += wsum[i];
    int excl = woff + x - v;
    cur[t] = excl;
    if (t < nn) {
        row_start[node0 + t] = base + excl;
        dinv[node0 + t] = rsqrtf((float)(v + 1));   // +1 self-loop
    }
    __syncthreads();
    for (int i = t; i < cnt; i += 512) {
        int pk = packed[base + i];
        int p = atomicAdd(&cur[pk & (BW - 1)], 1);
        sorted[p] = pk >> 9;
    }
    __syncthreads();
    for (int i = t; i < cnt; i += 512) sorted_src[base + i] = sorted[i];
}

// ---------- prescale: Xs[s] = bf16(dinv[s] * emb[s]) ----------
__global__ __launch_bounds__(256) void scale_emb(const float* __restrict__ emb,
                                                 const float* __restrict__ dinv,
                                                 unsigned short* __restrict__ Xs, int nq) {
    int q = blockIdx.x * 256 + threadIdx.x;      // one float4 (4 features)
    if (q >= nq) return;
    int node = q >> 4;                            // 16 float4 per row
    float d = dinv[node];
    float4 v = ((const float4*)emb)[q];
    ushort4 u;
    u.x = f2bf(v.x * d); u.y = f2bf(v.y * d);
    u.z = f2bf(v.z * d); u.w = f2bf(v.w * d);
    *(ushort4*)&Xs[(size_t)q * 4] = u;
}

// ---------- pull aggregation over pre-scaled bf16 rows ----------
// out[i] = dinv[i] * ( sum_{s in N(i)} Xs[s] + Xs[i] ) + bias
// wave = 1 node; lane: e = lane>>4 (4 edge slots), c = lane&15 (features 4c..4c+3)
// main loop: 8 edges in flight (two slot groups), guard-free; guarded 4-slot tail.
__global__ __launch_bounds__(256) void agg_bf16(const unsigned short* __restrict__ Xs,
                                                const float* __restrict__ dinv,
                                                const int* __restrict__ row_start,
                                                const int* __restrict__ sorted_src,
                                                const float* __restrict__ bias,
                                                float* __restrict__ out, int n) {
    int lane = threadIdx.x & 63;
    int wid = threadIdx.x >> 6;
    int wave = blockIdx.x * (blockDim.x >> 6) + wid;
    int nwaves = gridDim.x * (blockDim.x >> 6);
    int e = lane >> 4;
    int c = lane & 15;
    for (int i = wave; i < n; i += nwaves) {
        int s0 = row_start[i], s1 = row_start[i + 1];
        float di = dinv[i];                                              // hoisted
        ushort4 uself = *(const ushort4*)&Xs[(size_t)i * NF + 4 * c];    // hoisted
        float a0 = 0.f, a1 = 0.f, a2 = 0.f, a3 = 0.f;
        float g0 = 0.f, g1 = 0.f, g2 = 0.f, g3 = 0.f;
        int j = s0;
        for (; j + 8 <= s1; j += 8) {
            int sA = sorted_src[j + e];
            int sB = sorted_src[j + 4 + e];
            ushort4 uA = *(const ushort4*)&Xs[(size_t)sA * NF + 4 * c];
            ushort4 uB = *(const ushort4*)&Xs[(size_t)sB * NF + 4 * c];
            a0 += bf2f(uA.x); a1 += bf2f(uA.y); a2 += bf2f(uA.z); a3 += bf2f(uA.w);
            g0 += bf2f(uB.x); g1 += bf2f(uB.y); g2 += bf2f(uB.z); g3 += bf2f(uB.w);
        }
        for (; j < s1; j += 4) {
            int sj = j + e;
            if (sj < s1) {
                int s = sorted_src[sj];
                ushort4 u = *(const ushort4*)&Xs[(size_t)s * NF + 4 * c];
                a0 += bf2f(u.x); a1 += bf2f(u.y); a2 += bf2f(u.z); a3 += bf2f(u.w);
            }
        }
        a0 += g0; a1 += g1; a2 += g2; a3 += g3;
        a0 += __shfl_xor(a0, 16, 64); a1 += __shfl_xor(a1, 16, 64);
        a2 += __shfl_xor(a2, 16, 64); a3 += __shfl_xor(a3, 16, 64);
        a0 += __shfl_xor(a0, 32, 64); a1 += __shfl_xor(a1, 32, 64);
        a2 += __shfl_xor(a2, 32, 64); a3 += __shfl_xor(a3, 32, 64);
        if (e == 0) {
            a0 = di * (a0 + bf2f(uself.x));
            a1 = di * (a1 + bf2f(uself.y));
            a2 = di * (a2 + bf2f(uself.z));
            a3 = di * (a3 + bf2f(uself.w));
            if (bias) {
                float4 bb = *(const float4*)&bias[4 * c];
                a0 += bb.x; a1 += bb.y; a2 += bb.z; a3 += bb.w;
            }
            float4 o; o.x = a0; o.y = a1; o.z = a2; o.w = a3;
            *(float4*)&out[(size_t)i * NF + 4 * c] = o;
        }
    }
}

// ---------- fused register-tiled GEMM: Tbf = bf16( dinv[row] * (relu(A@W1+b1) @ W2) ) ----------
__global__ __launch_bounds__(256) void gemm_fused(const float* __restrict__ A,
                                                  const float* __restrict__ W1,
                                                  const float* __restrict__ b1,
                                                  const float* __restrict__ W2,
                                                  const float* __restrict__ dinv,
                                                  unsigned short* __restrict__ Tbf) {
    __shared__ float lds[12800];            // 50 KB
    float* ldsA = lds;                      // [64][36]  (phase 1)
    float* w1s  = lds + 2304;               // [64][128] (phase 1)
    float* w2s  = lds;                      // [128][64] (phase 2)
    float* hT   = lds + 8192;               // [128][36] (phase 2)

    const int t = threadIdx.x;
    const int r0 = blockIdx.x * 32;
    const int rg = t & 7;                   // rows 4rg .. 4rg+3
    const int cg = t >> 3;                  // phase1 cols 4cg..+3 ; phase2 cols 2cg..+1

    {
        const float4* Wv = (const float4*)W1;
        float4* dv = (float4*)w1s;
        #pragma unroll
        for (int i = 0; i < 8; ++i) dv[t + 256 * i] = Wv[t + 256 * i];
    }
    #pragma unroll
    for (int i = 0; i < 2; ++i) {
        int q = t + 256 * i;                // 512 float4s
        int row = q >> 4;
        int k0 = (q & 15) << 2;
        float4 v = *(const float4*)&A[(size_t)(r0 + row) * 64 + k0];
        ldsA[(k0 + 0) * 36 + row] = v.x;
        ldsA[(k0 + 1) * 36 + row] = v.y;
        ldsA[(k0 + 2) * 36 + row] = v.z;
        ldsA[(k0 + 3) * 36 + row] = v.w;
    }
    float b1a[4];
    {
        float4 b1v = *(const float4*)&b1[4 * cg];
        b1a[0] = b1v.x; b1a[1] = b1v.y; b1a[2] = b1v.z; b1a[3] = b1v.w;
    }
    __syncthreads();

    float acc[4][4];
    #pragma unroll
    for (int i = 0; i < 4; ++i)
        #pragma unroll
        for (int j = 0; j < 4; ++j) acc[i][j] = 0.f;
    #pragma unroll 4
    for (int k = 0; k < 64; ++k) {
        float4 a = *(float4*)&ldsA[k * 36 + 4 * rg];
        float4 w = *(float4*)&w1s[k * 128 + 4 * cg];
        acc[0][0] = fmaf(a.x, w.x, acc[0][0]); acc[0][1] = fmaf(a.x, w.y, acc[0][1]);
        acc[0][2] = fmaf(a.x, w.z, acc[0][2]); acc[0][3] = fmaf(a.x, w.w, acc[0][3]);
        acc[1][0] = fmaf(a.y, w.x, acc[1][0]); acc[1][1] = fmaf(a.y, w.y, acc[1][1]);
        acc[1][2] = fmaf(a.y, w.z, acc[1][2]); acc[1][3] = fmaf(a.y, w.w, acc[1][3]);
        acc[2][0] = fmaf(a.z, w.x, acc[2][0]); acc[2][1] = fmaf(a.z, w.y, acc[2][1]);
        acc[2][2] = fmaf(a.z, w.z, acc[2][2]); acc[2][3] = fmaf(a.z, w.w, acc[2][3]);
        acc[3][0] = fmaf(a.w, w.x, acc[3][0]); acc[3][1] = fmaf(a.w, w.y, acc[3][1]);
        acc[3][2] = fmaf(a.w, w.z, acc[3][2]); acc[3][3] = fmaf(a.w, w.w, acc[3][3]);
    }
    __syncthreads();

    #pragma unroll
    for (int jc = 0; jc < 4; ++jc) {
        float4 v;
        v.x = fmaxf(acc[0][jc] + b1a[jc], 0.f);
        v.y = fmaxf(acc[1][jc] + b1a[jc], 0.f);
        v.z = fmaxf(acc[2][jc] + b1a[jc], 0.f);
        v.w = fmaxf(acc[3][jc] + b1a[jc], 0.f);
        *(float4*)&hT[(4 * cg + jc) * 36 + 4 * rg] = v;
    }
    {
        const float4* Wv = (const float4*)W2;
        float4* dv = (float4*)w2s;
        #pragma unroll
        for (int i = 0; i < 8; ++i) dv[t + 256 * i] = Wv[t + 256 * i];
    }
    __syncthreads();

    float acc2[4][2];
    #pragma unroll
    for (int i = 0; i < 4; ++i) { acc2[i][0] = 0.f; acc2[i][1] = 0.f; }
    #pragma unroll 4
    for (int k = 0; k < 128; ++k) {
        float4 h = *(float4*)&hT[k * 36 + 4 * rg];
        float2 w = *(float2*)&w2s[k * 64 + 2 * cg];
        acc2[0][0] = fmaf(h.x, w.x, acc2[0][0]); acc2[0][1] = fmaf(h.x, w.y, acc2[0][1]);
        acc2[1][0] = fmaf(h.y, w.x, acc2[1][0]); acc2[1][1] = fmaf(h.y, w.y, acc2[1][1]);
        acc2[2][0] = fmaf(h.z, w.x, acc2[2][0]); acc2[2][1] = fmaf(h.z, w.y, acc2[2][1]);
        acc2[3][0] = fmaf(h.w, w.x, acc2[3][0]); acc2[3][1] = fmaf(h.w, w.y, acc2[3][1]);
    }
    #pragma unroll
    for (int i = 0; i < 4; ++i) {
        int r = r0 + 4 * rg + i;
        float d = dinv[r];
        ushort2 pk;
        pk.x = f2bf(acc2[i][0] * d);
        pk.y = f2bf(acc2[i][1] * d);
        *(ushort2*)&Tbf[(size_t)r * 64 + 2 * cg] = pk;
    }
}

extern "C" void kernel_launch(void* const* d_in, const int* in_sizes, int n_in,
                              void* d_out, int out_size, void* d_ws, size_t ws_size,
                              hipStream_t stream) {
    const int* edge = (const int*)d_in[0];       // int32 (JAX x64 disabled)
    const float* emb = (const float*)d_in[1];
    const float* W1  = (const float*)d_in[2];
    const float* b1  = (const float*)d_in[3];
    const float* W2  = (const float*)d_in[4];
    const float* b2  = (const float*)d_in[5];
    int E = in_sizes[0] / 2;
    const int* src = edge;
    const int* dst = edge + E;
    int n = N_NODES_C;

    char* p = (char*)d_ws;
    int*   row_start  = (int*)p;   p += align256((size_t)(n + 1) * 4);
    float* dinv       = (float*)p; p += align256((size_t)n * 4);
    int*   bcounts    = (int*)p;   p += align256(256 * 4);
    int*   base196    = (int*)p;   p += align256(256 * 4);
    int*   bucket_cur = (int*)p;   p += align256(256 * 4);
    int*   sorted_src = (int*)p;   p += align256((size_t)E * 4);
    float* agg1       = (float*)p; p += align256((size_t)n * NF * 4);
    unsigned short* Xs = (unsigned short*)p; p += align256((size_t)n * NF * 2);
    // packed aliases agg1: its lifetime [bin_kernel, bucket_sort_deg] ends before agg1 is written
    int* packed = (int*)agg1;

    hipMemsetAsync(bcounts, 0, NB * 4, stream);
    int nbin = (E + CHUNK - 1) / CHUNK;
    bucket_count<<<nbin, 1024, 0, stream>>>(dst, E, bcounts);
    scan196<<<1, 64, 0, stream>>>(bcounts, base196, bucket_cur, row_start, n);
    bin_kernel<<<nbin, 1024, 0, stream>>>(src, dst, E, bucket_cur, packed);
    bucket_sort_deg<<<NB, 512, 0, stream>>>(base196, packed, sorted_src, row_start, dinv, n);

    // prescale emb by dinv into bf16
    int nq = n * 16;   // float4 count
    scale_emb<<<(nq + 255) / 256, 256, 0, stream>>>(emb, dinv, Xs, nq);
    // layer 1 aggregation (64 wide), no bias -> agg1 (f32)
    agg_bf16<<<4096, 256, 0, stream>>>(Xs, dinv, row_start, sorted_src, nullptr, agg1, n);
    // fused GEMM: Xs <- bf16( dinv * (relu(agg1@W1+b1)@W2) )
    gemm_fused<<<3125, 256, 0, stream>>>(agg1, W1, b1, W2, dinv, Xs);
    // layer 2 aggregation + b2 -> out (f32)
    agg_bf16<<<4096, 256, 0, stream>>>(Xs, dinv, row_start, sorted_src, b2, (float*)d_out, n);
}

// Round 8
// 157.737 us; speedup vs baseline: 6.7968x; 1.2266x over previous
//
#include <hip/hip_runtime.h>
#include <cstdint>
#include <cstddef>

#define N_NODES_C 100000
#define NF 64      // feature width for both aggregations
#define BW 512     // bucket width (nodes)
#define NB 196     // ceil(100000/512)
#define CHUNK 8192 // edges per chunk block
#define SORT_CAP 9216

static inline size_t align256(size_t x) { return (x + 255) & ~size_t(255); }

typedef __attribute__((ext_vector_type(8))) short bf16x8;
typedef __attribute__((ext_vector_type(4))) float f32x4;

// bf16 helpers (RNE rounding)
__device__ inline float bf2f(unsigned short u) { return __uint_as_float(((unsigned)u) << 16); }
__device__ inline unsigned short f2bf(float x) {
    unsigned u = __float_as_uint(x);
    return (unsigned short)((u + 0x7fffu + ((u >> 16) & 1u)) >> 16);
}

// ---------- pass A: coarse bucket counts ----------
__global__ __launch_bounds__(1024) void bucket_count(const int* __restrict__ dst, int E,
                                                     int* __restrict__ counts) {
    __shared__ int hist[NB];
    int t = threadIdx.x;
    for (int i = t; i < NB; i += 1024) hist[i] = 0;
    __syncthreads();
    int e0 = blockIdx.x * CHUNK;
    int e1 = min(e0 + CHUNK, E);
    for (int e = e0 + t; e < e1; e += 1024) atomicAdd(&hist[dst[e] >> 9], 1);
    __syncthreads();
    for (int i = t; i < NB; i += 1024)
        if (hist[i]) atomicAdd(&counts[i], hist[i]);
}

// ---------- scan of 196 bucket counts (1 wave) ----------
__global__ void scan196(const int* __restrict__ counts, int* __restrict__ base196,
                        int* __restrict__ bucket_cursor, int* __restrict__ row_start, int n) {
    int lane = threadIdx.x;  // 64 threads
    int base = 0;
    for (int c = 0; c < NB; c += 64) {
        int idx = c + lane;
        int v = (idx < NB) ? counts[idx] : 0;
        int x = v;
        #pragma unroll
        for (int d = 1; d < 64; d <<= 1) {
            int y = __shfl_up(x, d, 64);
            if (lane >= d) x += y;
        }
        if (idx < NB) { base196[idx] = base + x - v; bucket_cursor[idx] = base + x - v; }
        base += __shfl(x, 63, 64);
    }
    if (lane == 0) { base196[NB] = base; row_start[n] = base; }
}

// ---------- pass B: coarse bucket binning, LDS-staged, coalesced output ----------
__global__ __launch_bounds__(1024) void bin_kernel(const int* __restrict__ src,
                                                   const int* __restrict__ dst, int E,
                                                   int* __restrict__ bucket_cursor,
                                                   int* __restrict__ packed) {
    __shared__ int hist[NB];
    __shared__ int lbase[NB];
    __shared__ int lcur[NB];
    __shared__ int gbase[NB];
    __shared__ int stage[CHUNK];
    __shared__ unsigned char bid[CHUNK];
    int t = threadIdx.x;
    int e0 = blockIdx.x * CHUNK;
    int e1 = min(e0 + CHUNK, E);
    for (int i = t; i < NB; i += 1024) hist[i] = 0;
    __syncthreads();
    for (int e = e0 + t; e < e1; e += 1024) atomicAdd(&hist[dst[e] >> 9], 1);
    __syncthreads();
    if (t < 64) {
        int base = 0;
        for (int c = 0; c < NB; c += 64) {
            int idx = c + t;
            int v = (idx < NB) ? hist[idx] : 0;
            int x = v;
            #pragma unroll
            for (int d = 1; d < 64; d <<= 1) {
                int y = __shfl_up(x, d, 64);
                if (t >= d) x += y;
            }
            if (idx < NB) { lbase[idx] = base + x - v; lcur[idx] = base + x - v; }
            base += __shfl(x, 63, 64);
        }
    }
    __syncthreads();
    if (t < NB) gbase[t] = atomicAdd(&bucket_cursor[t], hist[t]);
    for (int e = e0 + t; e < e1; e += 1024) {
        int d = dst[e];
        int b = d >> 9;
        int p = atomicAdd(&lcur[b], 1);
        stage[p] = (src[e] << 9) | (d & (BW - 1));
        bid[p] = (unsigned char)b;
    }
    __syncthreads();
    int cnt = e1 - e0;
    for (int i = t; i < cnt; i += 1024) {
        int b = bid[i];
        packed[gbase[b] + (i - lbase[b])] = stage[i];
    }
}

// ---------- pass C: per-bucket degree + row_start + dinv + counting sort ----------
__global__ __launch_bounds__(512) void bucket_sort_deg(const int* __restrict__ base196,
                                                       const int* __restrict__ packed,
                                                       int* __restrict__ sorted_src,
                                                       int* __restrict__ row_start,
                                                       float* __restrict__ dinv, int n) {
    __shared__ int hist[BW];
    __shared__ int cur[BW];
    __shared__ int wsum[8];
    __shared__ int sorted[SORT_CAP];
    int b = blockIdx.x;
    int node0 = b * BW;
    int nn = min(BW, n - node0);
    int base = base196[b];
    int end = base196[b + 1];
    int cnt = end - base;
    int t = threadIdx.x;
    hist[t] = 0;
    __syncthreads();
    for (int i = t; i < cnt; i += 512) atomicAdd(&hist[packed[base + i] & (BW - 1)], 1);
    __syncthreads();
    int v = hist[t];
    int lane = t & 63, w = t >> 6;
    int x = v;
    #pragma unroll
    for (int d = 1; d < 64; d <<= 1) {
        int y = __shfl_up(x, d, 64);
        if (lane >= d) x += y;
    }
    if (lane == 63) wsum[w] = x;
    __syncthreads();
    int woff = 0;
    for (int i = 0; i < w; ++i) woff += wsum[i];
    int excl = woff + x - v;
    cur[t] = excl;
    if (t < nn) {
        row_start[node0 + t] = base + excl;
        dinv[node0 + t] = rsqrtf((float)(v + 1));   // +1 self-loop
    }
    __syncthreads();
    for (int i = t; i < cnt; i += 512) {
        int pk = packed[base + i];
        int p = atomicAdd(&cur[pk & (BW - 1)], 1);
        sorted[p] = pk >> 9;
    }
    __syncthreads();
    for (int i = t; i < cnt; i += 512) sorted_src[base + i] = sorted[i];
}

// ---------- prep: weights -> bf16 MFMA B-fragment order ----------
// B-frag layout (16x16x32): col = lane&15, k = (lane>>4)*8 + j
__global__ __launch_bounds__(256) void prep_w(const float* __restrict__ W1,
                                              const float* __restrict__ W2,
                                              unsigned short* __restrict__ W1f,
                                              unsigned short* __restrict__ W2f) {
    int idx = blockIdx.x * 256 + threadIdx.x;   // grid 64 -> 16384
    int lane = (idx >> 3) & 63;
    int j = idx & 7;
    int kk = (lane >> 4) * 8 + j;
    int cb = lane & 15;
    if (idx < 8192) {
        int frag = idx >> 9;            // ct*2 + ks  (8 ct x 2 ks)
        int ct = frag >> 1, ks = frag & 1;
        W1f[idx] = f2bf(W1[(ks * 32 + kk) * 128 + ct * 16 + cb]);
    } else {
        int i2 = idx - 8192;
        int frag = i2 >> 9;             // ct*4 + ks  (4 ct x 4 ks)
        int ct = frag >> 2, ks = frag & 3;
        W2f[i2] = f2bf(W2[(ks * 32 + kk) * 64 + ct * 16 + cb]);
    }
}

// ---------- prescale: Xs[s] = bf16(dinv[s] * emb[s]) ----------
__global__ __launch_bounds__(256) void scale_emb(const float* __restrict__ emb,
                                                 const float* __restrict__ dinv,
                                                 unsigned short* __restrict__ Xs, int nq) {
    int q = blockIdx.x * 256 + threadIdx.x;
    if (q >= nq) return;
    int node = q >> 4;
    float d = dinv[node];
    float4 v = ((const float4*)emb)[q];
    ushort4 u;
    u.x = f2bf(v.x * d); u.y = f2bf(v.y * d);
    u.z = f2bf(v.z * d); u.w = f2bf(v.w * d);
    *(ushort4*)&Xs[(size_t)q * 4] = u;
}

// ---------- pull aggregation over pre-scaled bf16 rows ----------
// out[i] = dinv[i] * ( sum_{s in N(i)} Xs[s] + Xs[i] ) + bias
template<int OUTBF>
__global__ __launch_bounds__(256) void agg_bf16(const unsigned short* __restrict__ Xs,
                                                const float* __restrict__ dinv,
                                                const int* __restrict__ row_start,
                                                const int* __restrict__ sorted_src,
                                                const float* __restrict__ bias,
                                                void* __restrict__ outp, int n) {
    int lane = threadIdx.x & 63;
    int wid = threadIdx.x >> 6;
    int wave = blockIdx.x * (blockDim.x >> 6) + wid;
    int nwaves = gridDim.x * (blockDim.x >> 6);
    int e = lane >> 4;
    int c = lane & 15;
    for (int i = wave; i < n; i += nwaves) {
        int s0 = row_start[i], s1 = row_start[i + 1];
        float di = dinv[i];
        ushort4 uself = *(const ushort4*)&Xs[(size_t)i * NF + 4 * c];
        float a0 = 0.f, a1 = 0.f, a2 = 0.f, a3 = 0.f;
        float g0 = 0.f, g1 = 0.f, g2 = 0.f, g3 = 0.f;
        int j = s0;
        for (; j + 8 <= s1; j += 8) {
            int sA = sorted_src[j + e];
            int sB = sorted_src[j + 4 + e];
            ushort4 uA = *(const ushort4*)&Xs[(size_t)sA * NF + 4 * c];
            ushort4 uB = *(const ushort4*)&Xs[(size_t)sB * NF + 4 * c];
            a0 += bf2f(uA.x); a1 += bf2f(uA.y); a2 += bf2f(uA.z); a3 += bf2f(uA.w);
            g0 += bf2f(uB.x); g1 += bf2f(uB.y); g2 += bf2f(uB.z); g3 += bf2f(uB.w);
        }
        for (; j < s1; j += 4) {
            int sj = j + e;
            if (sj < s1) {
                int s = sorted_src[sj];
                ushort4 u = *(const ushort4*)&Xs[(size_t)s * NF + 4 * c];
                a0 += bf2f(u.x); a1 += bf2f(u.y); a2 += bf2f(u.z); a3 += bf2f(u.w);
            }
        }
        a0 += g0; a1 += g1; a2 += g2; a3 += g3;
        a0 += __shfl_xor(a0, 16, 64); a1 += __shfl_xor(a1, 16, 64);
        a2 += __shfl_xor(a2, 16, 64); a3 += __shfl_xor(a3, 16, 64);
        a0 += __shfl_xor(a0, 32, 64); a1 += __shfl_xor(a1, 32, 64);
        a2 += __shfl_xor(a2, 32, 64); a3 += __shfl_xor(a3, 32, 64);
        if (e == 0) {
            a0 = di * (a0 + bf2f(uself.x));
            a1 = di * (a1 + bf2f(uself.y));
            a2 = di * (a2 + bf2f(uself.z));
            a3 = di * (a3 + bf2f(uself.w));
            if (bias) {
                float4 bb = *(const float4*)&bias[4 * c];
                a0 += bb.x; a1 += bb.y; a2 += bb.z; a3 += bb.w;
            }
            if constexpr (OUTBF) {
                unsigned short* out = (unsigned short*)outp;
                ushort4 o;
                o.x = f2bf(a0); o.y = f2bf(a1); o.z = f2bf(a2); o.w = f2bf(a3);
                *(ushort4*)&out[(size_t)i * NF + 4 * c] = o;
            } else {
                float* out = (float*)outp;
                float4 o; o.x = a0; o.y = a1; o.z = a2; o.w = a3;
                *(float4*)&out[(size_t)i * NF + 4 * c] = o;
            }
        }
    }
}

// ---------- MFMA fused GEMM: Tbf = bf16( dinv[row] * (relu(A@W1+b1) @ W2) ) ----------
// 4 waves/block, wave = 16 rows. A bf16 from global (frag: row=lane&15, k=(lane>>4)*8+j).
// W from fragment-ordered bf16 arrays (L1-hot). h via wave-private LDS [16][136] bf16.
// D layout (HW-verified): col = lane&15, row = (lane>>4)*4 + reg.
__global__ __launch_bounds__(256) void gemm_mfma(const unsigned short* __restrict__ Abf,
                                                 const unsigned short* __restrict__ W1f,
                                                 const float* __restrict__ b1,
                                                 const unsigned short* __restrict__ W2f,
                                                 const float* __restrict__ dinv,
                                                 unsigned short* __restrict__ Tbf, int n) {
    __shared__ unsigned short h_all[4][16 * 136];
    const int t = threadIdx.x;
    const int wid = t >> 6, lane = t & 63;
    const int m = lane & 15, kg = lane >> 4;
    const int wrow = blockIdx.x * 64 + wid * 16;
    unsigned short* h_lds = h_all[wid];

    // A fragments (row-clamped for the tail block)
    int arow = wrow + m; if (arow >= n) arow = n - 1;
    bf16x8 a0 = *(const bf16x8*)&Abf[(size_t)arow * 64 + kg * 8];
    bf16x8 a1 = *(const bf16x8*)&Abf[(size_t)arow * 64 + 32 + kg * 8];

    // phase 1: h(16x128) = A(16x64)@W1, relu(+b1), to LDS as bf16
    #pragma unroll
    for (int ct = 0; ct < 8; ++ct) {
        f32x4 acc = {0.f, 0.f, 0.f, 0.f};
        bf16x8 w0 = *(const bf16x8*)&W1f[(ct * 2 + 0) * 512 + lane * 8];
        bf16x8 w1 = *(const bf16x8*)&W1f[(ct * 2 + 1) * 512 + lane * 8];
        acc = __builtin_amdgcn_mfma_f32_16x16x32_bf16(a0, w0, acc, 0, 0, 0);
        acc = __builtin_amdgcn_mfma_f32_16x16x32_bf16(a1, w1, acc, 0, 0, 0);
        float bb = b1[ct * 16 + m];
        #pragma unroll
        for (int r = 0; r < 4; ++r) {
            float v = fmaxf(acc[r] + bb, 0.f);
            h_lds[(kg * 4 + r) * 136 + ct * 16 + m] = f2bf(v);
        }
    }
    // wave-private LDS: no __syncthreads needed (compiler inserts lgkmcnt waits)

    // phase 2 A-fragments from h
    bf16x8 hf[4];
    #pragma unroll
    for (int ks = 0; ks < 4; ++ks)
        hf[ks] = *(const bf16x8*)&h_lds[m * 136 + ks * 32 + kg * 8];

    float dv[4];
    #pragma unroll
    for (int r = 0; r < 4; ++r) {
        int row = wrow + kg * 4 + r;
        dv[r] = (row < n) ? dinv[row] : 0.f;
    }
    #pragma unroll
    for (int ct = 0; ct < 4; ++ct) {
        f32x4 acc = {0.f, 0.f, 0.f, 0.f};
        #pragma unroll
        for (int ks = 0; ks < 4; ++ks) {
            bf16x8 w = *(const bf16x8*)&W2f[(ct * 4 + ks) * 512 + lane * 8];
            acc = __builtin_amdgcn_mfma_f32_16x16x32_bf16(hf[ks], w, acc, 0, 0, 0);
        }
        #pragma unroll
        for (int r = 0; r < 4; ++r) {
            int row = wrow + kg * 4 + r;
            if (row < n) Tbf[(size_t)row * 64 + ct * 16 + m] = f2bf(acc[r] * dv[r]);
        }
    }
}

extern "C" void kernel_launch(void* const* d_in, const int* in_sizes, int n_in,
                              void* d_out, int out_size, void* d_ws, size_t ws_size,
                              hipStream_t stream) {
    const int* edge = (const int*)d_in[0];       // int32 (JAX x64 disabled)
    const float* emb = (const float*)d_in[1];
    const float* W1  = (const float*)d_in[2];
    const float* b1  = (const float*)d_in[3];
    const float* W2  = (const float*)d_in[4];
    const float* b2  = (const float*)d_in[5];
    int E = in_sizes[0] / 2;
    const int* src = edge;
    const int* dst = edge + E;
    int n = N_NODES_C;

    char* p = (char*)d_ws;
    int*   row_start  = (int*)p;   p += align256((size_t)(n + 1) * 4);
    float* dinv       = (float*)p; p += align256((size_t)n * 4);
    int*   bcounts    = (int*)p;   p += align256(256 * 4);
    int*   base196    = (int*)p;   p += align256(256 * 4);
    int*   bucket_cur = (int*)p;   p += align256(256 * 4);
    unsigned short* W1f = (unsigned short*)p; p += align256(8192 * 2);
    unsigned short* W2f = (unsigned short*)p; p += align256(8192 * 2);
    int*   sorted_src = (int*)p;   p += align256((size_t)E * 4);
    unsigned short* Abf = (unsigned short*)p; p += align256((size_t)n * NF * 2);
    unsigned short* Xs  = (unsigned short*)p; p += align256((size_t)n * NF * 2);
    // packed aliases Abf: its lifetime [bin_kernel, bucket_sort_deg] ends before Abf is written
    int* packed = (int*)Abf;

    prep_w<<<64, 256, 0, stream>>>(W1, W2, W1f, W2f);
    hipMemsetAsync(bcounts, 0, NB * 4, stream);
    int nbin = (E + CHUNK - 1) / CHUNK;
    bucket_count<<<nbin, 1024, 0, stream>>>(dst, E, bcounts);
    scan196<<<1, 64, 0, stream>>>(bcounts, base196, bucket_cur, row_start, n);
    bin_kernel<<<nbin, 1024, 0, stream>>>(src, dst, E, bucket_cur, packed);
    bucket_sort_deg<<<NB, 512, 0, stream>>>(base196, packed, sorted_src, row_start, dinv, n);

    // prescale emb by dinv into bf16
    int nq = n * 16;
    scale_emb<<<(nq + 255) / 256, 256, 0, stream>>>(emb, dinv, Xs, nq);
    // layer 1 aggregation -> Abf (bf16)
    agg_bf16<1><<<4096, 256, 0, stream>>>(Xs, dinv, row_start, sorted_src, nullptr, Abf, n);
    // fused MFMA GEMM: Xs <- bf16( dinv * (relu(Abf@W1+b1)@W2) )   (Xs free: agg1 consumed it)
    gemm_mfma<<<(n + 63) / 64, 256, 0, stream>>>(Abf, W1f, b1, W2f, dinv, Xs, n);
    // layer 2 aggregation + b2 -> out (f32)
    agg_bf16<0><<<4096, 256, 0, stream>>>(Xs, dinv, row_start, sorted_src, b2, d_out, n);
}

// Round 9
// 150.600 us; speedup vs baseline: 7.1189x; 1.0474x over previous
//
#include <hip/hip_runtime.h>
#include <cstdint>
#include <cstddef>

#define N_NODES_C 100000
#define NF 64      // feature width for both aggregations
#define BW 512     // bucket width (nodes)
#define NB 196     // ceil(100000/512)
#define CHUNK 8192 // edges per chunk block
#define SORT_CAP 9216

static inline size_t align256(size_t x) { return (x + 255) & ~size_t(255); }

typedef __attribute__((ext_vector_type(8))) short bf16x8;
typedef __attribute__((ext_vector_type(4))) float f32x4;

// bf16 helpers (RNE rounding)
__device__ inline float bf2f(unsigned short u) { return __uint_as_float(((unsigned)u) << 16); }
__device__ inline unsigned short f2bf(float x) {
    unsigned u = __float_as_uint(x);
    return (unsigned short)((u + 0x7fffu + ((u >> 16) & 1u)) >> 16);
}

// ---------- pass A: coarse bucket counts ----------
__global__ __launch_bounds__(1024) void bucket_count(const int* __restrict__ dst, int E,
                                                     int* __restrict__ counts) {
    __shared__ int hist[NB];
    int t = threadIdx.x;
    for (int i = t; i < NB; i += 1024) hist[i] = 0;
    __syncthreads();
    int e0 = blockIdx.x * CHUNK;
    int e1 = min(e0 + CHUNK, E);
    for (int e = e0 + t; e < e1; e += 1024) atomicAdd(&hist[dst[e] >> 9], 1);
    __syncthreads();
    for (int i = t; i < NB; i += 1024)
        if (hist[i]) atomicAdd(&counts[i], hist[i]);
}

// ---------- scan of 196 bucket counts (1 wave) ----------
__global__ void scan196(const int* __restrict__ counts, int* __restrict__ base196,
                        int* __restrict__ bucket_cursor, int* __restrict__ row_start, int n) {
    int lane = threadIdx.x;  // 64 threads
    int base = 0;
    for (int c = 0; c < NB; c += 64) {
        int idx = c + lane;
        int v = (idx < NB) ? counts[idx] : 0;
        int x = v;
        #pragma unroll
        for (int d = 1; d < 64; d <<= 1) {
            int y = __shfl_up(x, d, 64);
            if (lane >= d) x += y;
        }
        if (idx < NB) { base196[idx] = base + x - v; bucket_cursor[idx] = base + x - v; }
        base += __shfl(x, 63, 64);
    }
    if (lane == 0) { base196[NB] = base; row_start[n] = base; }
}

// ---------- pass B: coarse bucket binning, LDS-staged, coalesced output ----------
__global__ __launch_bounds__(1024) void bin_kernel(const int* __restrict__ src,
                                                   const int* __restrict__ dst, int E,
                                                   int* __restrict__ bucket_cursor,
                                                   int* __restrict__ packed) {
    __shared__ int hist[NB];
    __shared__ int lbase[NB];
    __shared__ int lcur[NB];
    __shared__ int gbase[NB];
    __shared__ int stage[CHUNK];
    __shared__ unsigned char bid[CHUNK];
    int t = threadIdx.x;
    int e0 = blockIdx.x * CHUNK;
    int e1 = min(e0 + CHUNK, E);
    for (int i = t; i < NB; i += 1024) hist[i] = 0;
    __syncthreads();
    for (int e = e0 + t; e < e1; e += 1024) atomicAdd(&hist[dst[e] >> 9], 1);
    __syncthreads();
    if (t < 64) {
        int base = 0;
        for (int c = 0; c < NB; c += 64) {
            int idx = c + t;
            int v = (idx < NB) ? hist[idx] : 0;
            int x = v;
            #pragma unroll
            for (int d = 1; d < 64; d <<= 1) {
                int y = __shfl_up(x, d, 64);
                if (t >= d) x += y;
            }
            if (idx < NB) { lbase[idx] = base + x - v; lcur[idx] = base + x - v; }
            base += __shfl(x, 63, 64);
        }
    }
    __syncthreads();
    if (t < NB) gbase[t] = atomicAdd(&bucket_cursor[t], hist[t]);
    for (int e = e0 + t; e < e1; e += 1024) {
        int d = dst[e];
        int b = d >> 9;
        int p = atomicAdd(&lcur[b], 1);
        stage[p] = (src[e] << 9) | (d & (BW - 1));
        bid[p] = (unsigned char)b;
    }
    __syncthreads();
    int cnt = e1 - e0;
    for (int i = t; i < cnt; i += 1024) {
        int b = bid[i];
        packed[gbase[b] + (i - lbase[b])] = stage[i];
    }
}

// ---------- pass C: per-bucket degree + row_start + dinv + counting sort ----------
__global__ __launch_bounds__(512) void bucket_sort_deg(const int* __restrict__ base196,
                                                       const int* __restrict__ packed,
                                                       int* __restrict__ sorted_src,
                                                       int* __restrict__ row_start,
                                                       float* __restrict__ dinv, int n) {
    __shared__ int hist[BW];
    __shared__ int cur[BW];
    __shared__ int wsum[8];
    __shared__ int sorted[SORT_CAP];
    int b = blockIdx.x;
    int node0 = b * BW;
    int nn = min(BW, n - node0);
    int base = base196[b];
    int end = base196[b + 1];
    int cnt = end - base;
    int t = threadIdx.x;
    hist[t] = 0;
    __syncthreads();
    for (int i = t; i < cnt; i += 512) atomicAdd(&hist[packed[base + i] & (BW - 1)], 1);
    __syncthreads();
    int v = hist[t];
    int lane = t & 63, w = t >> 6;
    int x = v;
    #pragma unroll
    for (int d = 1; d < 64; d <<= 1) {
        int y = __shfl_up(x, d, 64);
        if (lane >= d) x += y;
    }
    if (lane == 63) wsum[w] = x;
    __syncthreads();
    int woff = 0;
    for (int i = 0; i < w; ++i) woff += wsum[i];
    int excl = woff + x - v;
    cur[t] = excl;
    if (t < nn) {
        row_start[node0 + t] = base + excl;
        dinv[node0 + t] = rsqrtf((float)(v + 1));   // +1 self-loop
    }
    __syncthreads();
    for (int i = t; i < cnt; i += 512) {
        int pk = packed[base + i];
        int p = atomicAdd(&cur[pk & (BW - 1)], 1);
        sorted[p] = pk >> 9;
    }
    __syncthreads();
    for (int i = t; i < cnt; i += 512) sorted_src[base + i] = sorted[i];
}

// ---------- prep: weights -> bf16 MFMA B-fragment order ----------
// B-frag layout (16x16x32): col = lane&15, k = (lane>>4)*8 + j
__global__ __launch_bounds__(256) void prep_w(const float* __restrict__ W1,
                                              const float* __restrict__ W2,
                                              unsigned short* __restrict__ W1f,
                                              unsigned short* __restrict__ W2f) {
    int idx = blockIdx.x * 256 + threadIdx.x;   // grid 64 -> 16384
    int lane = (idx >> 3) & 63;
    int j = idx & 7;
    int kk = (lane >> 4) * 8 + j;
    int cb = lane & 15;
    if (idx < 8192) {
        int frag = idx >> 9;            // ct*2 + ks  (8 ct x 2 ks)
        int ct = frag >> 1, ks = frag & 1;
        W1f[idx] = f2bf(W1[(ks * 32 + kk) * 128 + ct * 16 + cb]);
    } else {
        int i2 = idx - 8192;
        int frag = i2 >> 9;             // ct*4 + ks  (4 ct x 4 ks)
        int ct = frag >> 2, ks = frag & 3;
        W2f[i2] = f2bf(W2[(ks * 32 + kk) * 64 + ct * 16 + cb]);
    }
}

// ---------- prescale: Xs[s] = bf16(dinv[s] * emb[s]) ----------
__global__ __launch_bounds__(256) void scale_emb(const float* __restrict__ emb,
                                                 const float* __restrict__ dinv,
                                                 unsigned short* __restrict__ Xs, int nq) {
    int q = blockIdx.x * 256 + threadIdx.x;
    if (q >= nq) return;
    int node = q >> 4;
    float d = dinv[node];
    float4 v = ((const float4*)emb)[q];
    ushort4 u;
    u.x = f2bf(v.x * d); u.y = f2bf(v.y * d);
    u.z = f2bf(v.z * d); u.w = f2bf(v.w * d);
    *(ushort4*)&Xs[(size_t)q * 4] = u;
}

// ---------- pull aggregation over pre-scaled bf16 rows ----------
// out[i] = dinv[i] * ( sum_{s in N(i)} Xs[s] + Xs[i] ) + bias
// wave = 1 node; slot e = lane>>4 handles edges j+4e..j+4e+3; c = lane&15 -> features 4c..4c+3.
// Single fully-masked 16-edge loop: invalid lanes gather the zeroed pad row at Xs[-64].
template<int OUTBF>
__global__ __launch_bounds__(256) void agg_bf16(const unsigned short* __restrict__ Xs,
                                                const float* __restrict__ dinv,
                                                const int* __restrict__ row_start,
                                                const int* __restrict__ sorted_src,
                                                const float* __restrict__ bias,
                                                void* __restrict__ outp, int n) {
    int lane = threadIdx.x & 63;
    int wid = threadIdx.x >> 6;
    int wave = blockIdx.x * (blockDim.x >> 6) + wid;
    int nwaves = gridDim.x * (blockDim.x >> 6);
    int e = lane >> 4;
    int c = lane & 15;
    const int ZOFF = -64;   // element offset of the zeroed pad row
    for (int i = wave; i < n; i += nwaves) {
        int s0 = row_start[i], s1 = row_start[i + 1];
        float di = dinv[i];
        ushort4 uself = *(const ushort4*)&Xs[(size_t)i * NF + 4 * c];
        float a0 = 0.f, a1 = 0.f, a2 = 0.f, a3 = 0.f;
        float g0 = 0.f, g1 = 0.f, g2 = 0.f, g3 = 0.f;
        for (int j = s0; j < s1; j += 16) {
            int b0 = j + 4 * e;
            int sj0 = b0, sj1 = b0 + 1, sj2 = b0 + 2, sj3 = b0 + 3;
            int i0 = sorted_src[min(sj0, s1 - 1)];
            int i1 = sorted_src[min(sj1, s1 - 1)];
            int i2 = sorted_src[min(sj2, s1 - 1)];
            int i3 = sorted_src[min(sj3, s1 - 1)];
            int o0 = (sj0 < s1) ? (i0 << 6) : ZOFF;
            int o1 = (sj1 < s1) ? (i1 << 6) : ZOFF;
            int o2 = (sj2 < s1) ? (i2 << 6) : ZOFF;
            int o3 = (sj3 < s1) ? (i3 << 6) : ZOFF;
            ushort4 u0 = *(const ushort4*)(Xs + o0 + 4 * c);
            ushort4 u1 = *(const ushort4*)(Xs + o1 + 4 * c);
            ushort4 u2 = *(const ushort4*)(Xs + o2 + 4 * c);
            ushort4 u3 = *(const ushort4*)(Xs + o3 + 4 * c);
            a0 += bf2f(u0.x); a1 += bf2f(u0.y); a2 += bf2f(u0.z); a3 += bf2f(u0.w);
            g0 += bf2f(u1.x); g1 += bf2f(u1.y); g2 += bf2f(u1.z); g3 += bf2f(u1.w);
            a0 += bf2f(u2.x); a1 += bf2f(u2.y); a2 += bf2f(u2.z); a3 += bf2f(u2.w);
            g0 += bf2f(u3.x); g1 += bf2f(u3.y); g2 += bf2f(u3.z); g3 += bf2f(u3.w);
        }
        a0 += g0; a1 += g1; a2 += g2; a3 += g3;
        a0 += __shfl_xor(a0, 16, 64); a1 += __shfl_xor(a1, 16, 64);
        a2 += __shfl_xor(a2, 16, 64); a3 += __shfl_xor(a3, 16, 64);
        a0 += __shfl_xor(a0, 32, 64); a1 += __shfl_xor(a1, 32, 64);
        a2 += __shfl_xor(a2, 32, 64); a3 += __shfl_xor(a3, 32, 64);
        if (e == 0) {
            a0 = di * (a0 + bf2f(uself.x));
            a1 = di * (a1 + bf2f(uself.y));
            a2 = di * (a2 + bf2f(uself.z));
            a3 = di * (a3 + bf2f(uself.w));
            if (bias) {
                float4 bb = *(const float4*)&bias[4 * c];
                a0 += bb.x; a1 += bb.y; a2 += bb.z; a3 += bb.w;
            }
            if constexpr (OUTBF) {
                unsigned short* out = (unsigned short*)outp;
                ushort4 o;
                o.x = f2bf(a0); o.y = f2bf(a1); o.z = f2bf(a2); o.w = f2bf(a3);
                *(ushort4*)&out[(size_t)i * NF + 4 * c] = o;
            } else {
                float* out = (float*)outp;
                float4 o; o.x = a0; o.y = a1; o.z = a2; o.w = a3;
                *(float4*)&out[(size_t)i * NF + 4 * c] = o;
            }
        }
    }
}

// ---------- MFMA fused GEMM: Tbf = bf16( dinv[row] * (relu(A@W1+b1) @ W2) ) ----------
__global__ __launch_bounds__(256) void gemm_mfma(const unsigned short* __restrict__ Abf,
                                                 const unsigned short* __restrict__ W1f,
                                                 const float* __restrict__ b1,
                                                 const unsigned short* __restrict__ W2f,
                                                 const float* __restrict__ dinv,
                                                 unsigned short* __restrict__ Tbf, int n) {
    __shared__ unsigned short h_all[4][16 * 136];
    const int t = threadIdx.x;
    const int wid = t >> 6, lane = t & 63;
    const int m = lane & 15, kg = lane >> 4;
    const int wrow = blockIdx.x * 64 + wid * 16;
    unsigned short* h_lds = h_all[wid];

    int arow = wrow + m; if (arow >= n) arow = n - 1;
    bf16x8 a0 = *(const bf16x8*)&Abf[(size_t)arow * 64 + kg * 8];
    bf16x8 a1 = *(const bf16x8*)&Abf[(size_t)arow * 64 + 32 + kg * 8];

    #pragma unroll
    for (int ct = 0; ct < 8; ++ct) {
        f32x4 acc = {0.f, 0.f, 0.f, 0.f};
        bf16x8 w0 = *(const bf16x8*)&W1f[(ct * 2 + 0) * 512 + lane * 8];
        bf16x8 w1 = *(const bf16x8*)&W1f[(ct * 2 + 1) * 512 + lane * 8];
        acc = __builtin_amdgcn_mfma_f32_16x16x32_bf16(a0, w0, acc, 0, 0, 0);
        acc = __builtin_amdgcn_mfma_f32_16x16x32_bf16(a1, w1, acc, 0, 0, 0);
        float bb = b1[ct * 16 + m];
        #pragma unroll
        for (int r = 0; r < 4; ++r) {
            float v = fmaxf(acc[r] + bb, 0.f);
            h_lds[(kg * 4 + r) * 136 + ct * 16 + m] = f2bf(v);
        }
    }

    bf16x8 hf[4];
    #pragma unroll
    for (int ks = 0; ks < 4; ++ks)
        hf[ks] = *(const bf16x8*)&h_lds[m * 136 + ks * 32 + kg * 8];

    float dv[4];
    #pragma unroll
    for (int r = 0; r < 4; ++r) {
        int row = wrow + kg * 4 + r;
        dv[r] = (row < n) ? dinv[row] : 0.f;
    }
    #pragma unroll
    for (int ct = 0; ct < 4; ++ct) {
        f32x4 acc = {0.f, 0.f, 0.f, 0.f};
        #pragma unroll
        for (int ks = 0; ks < 4; ++ks) {
            bf16x8 w = *(const bf16x8*)&W2f[(ct * 4 + ks) * 512 + lane * 8];
            acc = __builtin_amdgcn_mfma_f32_16x16x32_bf16(hf[ks], w, acc, 0, 0, 0);
        }
        #pragma unroll
        for (int r = 0; r < 4; ++r) {
            int row = wrow + kg * 4 + r;
            if (row < n) Tbf[(size_t)row * 64 + ct * 16 + m] = f2bf(acc[r] * dv[r]);
        }
    }
}

extern "C" void kernel_launch(void* const* d_in, const int* in_sizes, int n_in,
                              void* d_out, int out_size, void* d_ws, size_t ws_size,
                              hipStream_t stream) {
    const int* edge = (const int*)d_in[0];       // int32 (JAX x64 disabled)
    const float* emb = (const float*)d_in[1];
    const float* W1  = (const float*)d_in[2];
    const float* b1  = (const float*)d_in[3];
    const float* W2  = (const float*)d_in[4];
    const float* b2  = (const float*)d_in[5];
    int E = in_sizes[0] / 2;
    const int* src = edge;
    const int* dst = edge + E;
    int n = N_NODES_C;

    char* p = (char*)d_ws;
    int*   row_start  = (int*)p;   p += align256((size_t)(n + 1) * 4);
    float* dinv       = (float*)p; p += align256((size_t)n * 4);
    int*   bcounts    = (int*)p;   p += align256(256 * 4);
    int*   base196    = (int*)p;   p += align256(256 * 4);
    int*   bucket_cur = (int*)p;   p += align256(256 * 4);
    unsigned short* W1f = (unsigned short*)p; p += align256(8192 * 2);
    unsigned short* W2f = (unsigned short*)p; p += align256(8192 * 2);
    int*   sorted_src = (int*)p;   p += align256((size_t)E * 4);
    char*  zpadA      = p;         p += 256;   // zero pad row for Abf
    unsigned short* Abf = (unsigned short*)p; p += align256((size_t)n * NF * 2);
    char*  zpadX      = p;         p += 256;   // zero pad row for Xs
    unsigned short* Xs  = (unsigned short*)p; p += align256((size_t)n * NF * 2);
    // packed aliases Abf: its lifetime [bin_kernel, bucket_sort_deg] ends before Abf is written
    int* packed = (int*)Abf;

    prep_w<<<64, 256, 0, stream>>>(W1, W2, W1f, W2f);
    hipMemsetAsync(bcounts, 0, NB * 4, stream);
    hipMemsetAsync(zpadA, 0, 256, stream);
    hipMemsetAsync(zpadX, 0, 256, stream);
    int nbin = (E + CHUNK - 1) / CHUNK;
    bucket_count<<<nbin, 1024, 0, stream>>>(dst, E, bcounts);
    scan196<<<1, 64, 0, stream>>>(bcounts, base196, bucket_cur, row_start, n);
    bin_kernel<<<nbin, 1024, 0, stream>>>(src, dst, E, bucket_cur, packed);
    bucket_sort_deg<<<NB, 512, 0, stream>>>(base196, packed, sorted_src, row_start, dinv, n);

    // prescale emb by dinv into bf16
    int nq = n * 16;
    scale_emb<<<(nq + 255) / 256, 256, 0, stream>>>(emb, dinv, Xs, nq);
    // layer 1 aggregation -> Abf (bf16)   (zpadA re-zeroed implicitly never written after memset)
    agg_bf16<1><<<4096, 256, 0, stream>>>(Xs, dinv, row_start, sorted_src, nullptr, Abf, n);
    // fused MFMA GEMM: Xs <- bf16( dinv * (relu(Abf@W1+b1)@W2) )
    gemm_mfma<<<(n + 63) / 64, 256, 0, stream>>>(Abf, W1f, b1, W2f, dinv, Xs, n);
    // layer 2 aggregation + b2 -> out (f32); gathers from Xs (zpadX is its zero row)
    agg_bf16<0><<<4096, 256, 0, stream>>>(Xs, dinv, row_start, sorted_src, b2, d_out, n);
}